// Round 1
// baseline (974.058 us; speedup 1.0000x reference)
//
#include <hip/hip_runtime.h>

#define NQ 12

struct C2 { float r, i; };
__device__ __forceinline__ C2 cmul(C2 a, C2 b){ return C2{a.r*b.r - a.i*b.i, a.r*b.i + a.i*b.r}; }
__device__ __forceinline__ C2 cadd(C2 a, C2 b){ return C2{a.r + b.r, a.i + b.i}; }

// Precompute the 24 fused per-wire unitaries G = RZ(c) * RY(b) * RX(a)
// (layer-major: t = layer*12 + wire), stored as 8 floats each in d_ws.
__global__ void precompute_gates(const float* __restrict__ wts, float* __restrict__ gout){
    int t = threadIdx.x;
    if (t >= 2*NQ) return;
    float a = wts[3*t], bb = wts[3*t+1], c = wts[3*t+2];
    float sa, ca, sb, cb, sc, cc;
    sincosf(0.5f*a,  &sa, &ca);
    sincosf(0.5f*bb, &sb, &cb);
    sincosf(0.5f*c,  &sc, &cc);
    // RX = [[ca, -i sa], [-i sa, ca]]
    C2 rx00{ca,0.f}, rx01{0.f,-sa}, rx10{0.f,-sa}, rx11{ca,0.f};
    // RY = [[cb, -sb], [sb, cb]]
    C2 ry00{cb,0.f}, ry01{-sb,0.f}, ry10{sb,0.f}, ry11{cb,0.f};
    // M = RY*RX
    C2 m00 = cadd(cmul(ry00,rx00), cmul(ry01,rx10));
    C2 m01 = cadd(cmul(ry00,rx01), cmul(ry01,rx11));
    C2 m10 = cadd(cmul(ry10,rx00), cmul(ry11,rx10));
    C2 m11 = cadd(cmul(ry10,rx01), cmul(ry11,rx11));
    // RZ = diag(e^{-ic/2}, e^{+ic/2})
    C2 e0{cc,-sc}, e1{cc,sc};
    C2 g00 = cmul(e0,m00), g01 = cmul(e0,m01);
    C2 g10 = cmul(e1,m10), g11 = cmul(e1,m11);
    float* o = gout + t*8;
    o[0]=g00.r; o[1]=g00.i; o[2]=g01.r; o[3]=g01.i;
    o[4]=g10.r; o[5]=g10.i; o[6]=g11.r; o[7]=g11.i;
}

// Apply layer-1 gate on wire W (0..5): in-lane pairs with slot stride D = 2^(5-W).
template<int W>
__device__ __forceinline__ void inlane_gate(float (&sr)[64], float (&si)[64], const float* __restrict__ g){
    float g00r=g[0], g00i=g[1], g01r=g[2], g01i=g[3];
    float g10r=g[4], g10i=g[5], g11r=g[6], g11i=g[7];
    constexpr int D = 1 << (5 - W);
    #pragma unroll
    for (int m = 0; m < 32; ++m){
        const int j0 = ((m & ~(D-1)) << 1) | (m & (D-1));
        const int j1 = j0 + D;
        float a0r=sr[j0], a0i=si[j0], a1r=sr[j1], a1i=si[j1];
        sr[j0] = g00r*a0r - g00i*a0i + g01r*a1r - g01i*a1i;
        si[j0] = g00r*a0i + g00i*a0r + g01r*a1i + g01i*a1r;
        sr[j1] = g10r*a0r - g10i*a0i + g11r*a1r - g11i*a1i;
        si[j1] = g10r*a0i + g10i*a0r + g11r*a1i + g11i*a1r;
    }
}

// One wave (64 lanes) simulates one batch element. State index k = 64*j + lane,
// lane = wires 6..11 (bit 5..0), slot j = wires 0..5 (bit 5..0 of j).
// state[k] = p[gray(k)] folds the layer-0 CNOT chain; measurement signs use
// prefix-xor parities to fold the layer-1 CNOT chain.
__global__ __launch_bounds__(256, 2)
void qsim(const float* __restrict__ x, const float* __restrict__ Gm,
          float* __restrict__ out, int B){
    const int lane = threadIdx.x & 63;
    const int wid  = threadIdx.x >> 6;
    const int b    = blockIdx.x * 4 + wid;
    if (b >= B) return;
    const float* xp = x + (size_t)b * NQ;

    // v_w = G0_w * [cos(x/2), sin(x/2)]^T  (wave-uniform values)
    float vr[12][2], vi[12][2];
    #pragma unroll
    for (int w = 0; w < 12; ++w){
        float sx, cx;
        __sincosf(0.5f * xp[w], &sx, &cx);
        const float* g = Gm + w*8;
        vr[w][0] = g[0]*cx + g[2]*sx;
        vi[w][0] = g[1]*cx + g[3]*sx;
        vr[w][1] = g[4]*cx + g[6]*sx;
        vi[w][1] = g[5]*cx + g[7]*sx;
    }

    // Low-product over wires 7..11 from gray bits of lane: bit m of g = l_m ^ l_{m+1}
    float lpr = 1.f, lpi = 0.f;
    #pragma unroll
    for (int m = 0; m <= 4; ++m){
        const int w = 11 - m;
        int bit = ((lane >> m) ^ (lane >> (m+1))) & 1;
        float ar = bit ? vr[w][1] : vr[w][0];
        float ai = bit ? vi[w][1] : vi[w][0];
        float nr = lpr*ar - lpi*ai;
        float ni = lpr*ai + lpi*ar;
        lpr = nr; lpi = ni;
    }
    // wire 6 bit of gray = l5 ^ j0 -> two variants selected by slot parity
    const int l5 = (lane >> 5) & 1;
    float a6r0 = l5 ? vr[6][1] : vr[6][0];
    float a6i0 = l5 ? vi[6][1] : vi[6][0];
    float a6r1 = l5 ? vr[6][0] : vr[6][1];
    float a6i1 = l5 ? vi[6][0] : vi[6][1];
    float lp0r = lpr*a6r0 - lpi*a6i0, lp0i = lpr*a6i0 + lpi*a6r0;
    float lp1r = lpr*a6r1 - lpi*a6i1, lp1i = lpr*a6i1 + lpi*a6r1;

    // High-product H'[j] = prod_t v_{5-t}[ j_t ^ j_{t+1} ] via in-place doubling (MSB first).
    float sr[64], si[64];
    sr[0] = vr[0][0]; si[0] = vi[0][0];
    sr[1] = vr[0][1]; si[1] = vi[0][1];
    #pragma unroll
    for (int t = 4; t >= 0; --t){
        const int q = 5 - t;            // wire index for this stage
        const int size = 1 << (6 - t);
        #pragma unroll
        for (int idx = size-1; idx >= 0; --idx){
            const int src  = idx >> 1;
            const int bsel = (idx & 1) ^ ((idx >> 1) & 1);
            float ar = vr[q][bsel], ai = vi[q][bsel];
            float nr = sr[src]*ar - si[src]*ai;
            float ni = sr[src]*ai + si[src]*ar;
            sr[idx] = nr; si[idx] = ni;
        }
    }
    // state = H' * LP(lane, j0)
    #pragma unroll
    for (int j = 0; j < 64; ++j){
        float br = (j & 1) ? lp1r : lp0r;
        float bi = (j & 1) ? lp1i : lp0i;
        float nr = sr[j]*br - si[j]*bi;
        float ni = sr[j]*bi + si[j]*br;
        sr[j] = nr; si[j] = ni;
    }

    // Layer-1 rotations, wires 0..5: in-lane
    inlane_gate<0>(sr, si, Gm + (12+0)*8);
    inlane_gate<1>(sr, si, Gm + (12+1)*8);
    inlane_gate<2>(sr, si, Gm + (12+2)*8);
    inlane_gate<3>(sr, si, Gm + (12+3)*8);
    inlane_gate<4>(sr, si, Gm + (12+4)*8);
    inlane_gate<5>(sr, si, Gm + (12+5)*8);

    // Wires 6..11: cross-lane pairs via shfl_xor
    #pragma unroll 1
    for (int w = 6; w < 12; ++w){
        const float* g = Gm + (12+w)*8;
        const int shift = 11 - w;
        const int xm = 1 << shift;
        const int myBit = (lane >> shift) & 1;
        float g00r=g[0], g00i=g[1], g01r=g[2], g01i=g[3];
        float g10r=g[4], g10i=g[5], g11r=g[6], g11i=g[7];
        float gar = myBit ? g11r : g00r;
        float gai = myBit ? g11i : g00i;
        float gbr = myBit ? g10r : g01r;
        float gbi = myBit ? g10i : g01i;
        #pragma unroll
        for (int j = 0; j < 64; ++j){
            float orr = __shfl_xor(sr[j], xm);
            float oii = __shfl_xor(si[j], xm);
            float nr = gar*sr[j] - gai*si[j] + gbr*orr - gbi*oii;
            float ni = gar*si[j] + gai*sr[j] + gbr*oii + gbi*orr;
            sr[j] = nr; si[j] = ni;
        }
    }

    // Measurement: <Z_w> = sum_k |s[k]|^2 * (-1)^{parity(k >> (11-w))}
    float s0=0.f,s1=0.f,s2=0.f,s3=0.f,s4=0.f,s5=0.f;
    #pragma unroll
    for (int j = 0; j < 64; ++j){
        float p = sr[j]*sr[j] + si[j]*si[j];
        s0 += (__builtin_popcount((unsigned)(j>>5)) & 1) ? -p : p;
        s1 += (__builtin_popcount((unsigned)(j>>4)) & 1) ? -p : p;
        s2 += (__builtin_popcount((unsigned)(j>>3)) & 1) ? -p : p;
        s3 += (__builtin_popcount((unsigned)(j>>2)) & 1) ? -p : p;
        s4 += (__builtin_popcount((unsigned)(j>>1)) & 1) ? -p : p;
        s5 += (__builtin_popcount((unsigned)(j   )) & 1) ? -p : p;
    }
    const float T = s5;   // full-j-parity signed sum, shared by wires 6..11
    float r0=s0, r1=s1, r2=s2, r3=s3, r4=s4, r5=s5;
    float r6  = (__builtin_popcount((unsigned)(lane>>5)) & 1) ? -T : T;
    float r7  = (__builtin_popcount((unsigned)(lane>>4)) & 1) ? -T : T;
    float r8  = (__builtin_popcount((unsigned)(lane>>3)) & 1) ? -T : T;
    float r9  = (__builtin_popcount((unsigned)(lane>>2)) & 1) ? -T : T;
    float r10 = (__builtin_popcount((unsigned)(lane>>1)) & 1) ? -T : T;
    float r11 = (__builtin_popcount((unsigned)(lane   )) & 1) ? -T : T;

    #pragma unroll
    for (int d = 1; d < 64; d <<= 1){
        r0  += __shfl_xor(r0,  d);
        r1  += __shfl_xor(r1,  d);
        r2  += __shfl_xor(r2,  d);
        r3  += __shfl_xor(r3,  d);
        r4  += __shfl_xor(r4,  d);
        r5  += __shfl_xor(r5,  d);
        r6  += __shfl_xor(r6,  d);
        r7  += __shfl_xor(r7,  d);
        r8  += __shfl_xor(r8,  d);
        r9  += __shfl_xor(r9,  d);
        r10 += __shfl_xor(r10, d);
        r11 += __shfl_xor(r11, d);
    }
    if (lane == 0){
        float* o = out + (size_t)b * NQ;
        o[0]=r0; o[1]=r1; o[2]=r2; o[3]=r3; o[4]=r4; o[5]=r5;
        o[6]=r6; o[7]=r7; o[8]=r8; o[9]=r9; o[10]=r10; o[11]=r11;
    }
}

extern "C" void kernel_launch(void* const* d_in, const int* in_sizes, int n_in,
                              void* d_out, int out_size, void* d_ws, size_t ws_size,
                              hipStream_t stream){
    const float* x   = (const float*)d_in[0];
    const float* wts = (const float*)d_in[1];
    float* out = (float*)d_out;
    float* gbuf = (float*)d_ws;           // 24 gates * 8 floats = 768 B
    const int B = in_sizes[0] / NQ;

    precompute_gates<<<1, 64, 0, stream>>>(wts, gbuf);
    qsim<<<(B + 3) / 4, 256, 0, stream>>>(x, gbuf, out, B);
}

// Round 2
// 266.310 us; speedup vs baseline: 3.6576x; 3.6576x over previous
//
#include <hip/hip_runtime.h>

#define NQ 12

struct C2 { float r, i; };
__device__ __forceinline__ C2 cmul(C2 a, C2 b){ return C2{a.r*b.r - a.i*b.i, a.r*b.i + a.i*b.r}; }
__device__ __forceinline__ C2 cadd(C2 a, C2 b){ return C2{a.r + b.r, a.i + b.i}; }

// Precompute the 24 fused per-wire unitaries G = RZ(c) * RY(b) * RX(a)
// (layer-major: t = layer*12 + wire), stored as 8 floats each in d_ws.
__global__ void precompute_gates(const float* __restrict__ wts, float* __restrict__ gout){
    int t = threadIdx.x;
    if (t >= 2*NQ) return;
    float a = wts[3*t], bb = wts[3*t+1], c = wts[3*t+2];
    float sa, ca, sb, cb, sc, cc;
    sincosf(0.5f*a,  &sa, &ca);
    sincosf(0.5f*bb, &sb, &cb);
    sincosf(0.5f*c,  &sc, &cc);
    // RX = [[ca, -i sa], [-i sa, ca]]
    C2 rx00{ca,0.f}, rx01{0.f,-sa}, rx10{0.f,-sa}, rx11{ca,0.f};
    // RY = [[cb, -sb], [sb, cb]]
    C2 ry00{cb,0.f}, ry01{-sb,0.f}, ry10{sb,0.f}, ry11{cb,0.f};
    // M = RY*RX
    C2 m00 = cadd(cmul(ry00,rx00), cmul(ry01,rx10));
    C2 m01 = cadd(cmul(ry00,rx01), cmul(ry01,rx11));
    C2 m10 = cadd(cmul(ry10,rx00), cmul(ry11,rx10));
    C2 m11 = cadd(cmul(ry10,rx01), cmul(ry11,rx11));
    // RZ = diag(e^{-ic/2}, e^{+ic/2})
    C2 e0{cc,-sc}, e1{cc,sc};
    C2 g00 = cmul(e0,m00), g01 = cmul(e0,m01);
    C2 g10 = cmul(e1,m10), g11 = cmul(e1,m11);
    float* o = gout + t*8;
    o[0]=g00.r; o[1]=g00.i; o[2]=g01.r; o[3]=g01.i;
    o[4]=g10.r; o[5]=g10.i; o[6]=g11.r; o[7]=g11.i;
}

// Apply layer-1 gate on wire W (0..5): in-lane pairs with slot stride D = 2^(5-W).
template<int W>
__device__ __forceinline__ void inlane_gate(float (&sr)[64], float (&si)[64], const float* __restrict__ g){
    float g00r=g[0], g00i=g[1], g01r=g[2], g01i=g[3];
    float g10r=g[4], g10i=g[5], g11r=g[6], g11i=g[7];
    constexpr int D = 1 << (5 - W);
    #pragma unroll
    for (int m = 0; m < 32; ++m){
        const int j0 = ((m & ~(D-1)) << 1) | (m & (D-1));
        const int j1 = j0 + D;
        float a0r=sr[j0], a0i=si[j0], a1r=sr[j1], a1i=si[j1];
        sr[j0] = g00r*a0r - g00i*a0i + g01r*a1r - g01i*a1i;
        si[j0] = g00r*a0i + g00i*a0r + g01r*a1i + g01i*a1r;
        sr[j1] = g10r*a0r - g10i*a0i + g11r*a1r - g11i*a1i;
        si[j1] = g10r*a0i + g10i*a0r + g11r*a1i + g11i*a1r;
    }
}

// One wave (64 lanes) simulates one batch element. State index k = 64*j + lane,
// lane = wires 6..11 (bit 5..0), slot j = wires 0..5 (bit 5..0 of j).
// state[k] = p[gray(k)] folds the layer-0 CNOT chain; measurement signs use
// prefix-xor parities to fold the layer-1 CNOT chain.
//
// __launch_bounds__(256, 1): the state lives in 128 VGPRs (sr+si) plus ~60
// more for gates/temps. Capping at 2 waves/EU (previous round) forced a
// 128-VGPR limit -> full state spilled to scratch -> 4.7 GB HBM traffic and
// 1 ms runtime. (256,1) allows up to 512 VGPRs; expected alloc ~240.
__global__ __launch_bounds__(256, 1)
void qsim(const float* __restrict__ x, const float* __restrict__ Gm,
          float* __restrict__ out, int B){
    const int lane = threadIdx.x & 63;
    const int wid  = threadIdx.x >> 6;
    const int b    = blockIdx.x * 4 + wid;
    if (b >= B) return;
    const float* xp = x + (size_t)b * NQ;

    // v_w = G0_w * [cos(x/2), sin(x/2)]^T  (wave-uniform values)
    float vr[12][2], vi[12][2];
    #pragma unroll
    for (int w = 0; w < 12; ++w){
        float sx, cx;
        __sincosf(0.5f * xp[w], &sx, &cx);
        const float* g = Gm + w*8;
        vr[w][0] = g[0]*cx + g[2]*sx;
        vi[w][0] = g[1]*cx + g[3]*sx;
        vr[w][1] = g[4]*cx + g[6]*sx;
        vi[w][1] = g[5]*cx + g[7]*sx;
    }

    // Low-product over wires 7..11 from gray bits of lane: bit m of g = l_m ^ l_{m+1}
    float lpr = 1.f, lpi = 0.f;
    #pragma unroll
    for (int m = 0; m <= 4; ++m){
        const int w = 11 - m;
        int bit = ((lane >> m) ^ (lane >> (m+1))) & 1;
        float ar = bit ? vr[w][1] : vr[w][0];
        float ai = bit ? vi[w][1] : vi[w][0];
        float nr = lpr*ar - lpi*ai;
        float ni = lpr*ai + lpi*ar;
        lpr = nr; lpi = ni;
    }
    // wire 6 bit of gray = l5 ^ j0 -> two variants selected by slot parity
    const int l5 = (lane >> 5) & 1;
    float a6r0 = l5 ? vr[6][1] : vr[6][0];
    float a6i0 = l5 ? vi[6][1] : vi[6][0];
    float a6r1 = l5 ? vr[6][0] : vr[6][1];
    float a6i1 = l5 ? vi[6][0] : vi[6][1];
    float lp0r = lpr*a6r0 - lpi*a6i0, lp0i = lpr*a6i0 + lpi*a6r0;
    float lp1r = lpr*a6r1 - lpi*a6i1, lp1i = lpr*a6i1 + lpi*a6r1;

    // High-product H'[j] = prod_t v_{5-t}[ j_t ^ j_{t+1} ] via in-place doubling (MSB first).
    float sr[64], si[64];
    sr[0] = vr[0][0]; si[0] = vi[0][0];
    sr[1] = vr[0][1]; si[1] = vi[0][1];
    #pragma unroll
    for (int t = 4; t >= 0; --t){
        const int q = 5 - t;            // wire index for this stage
        const int size = 1 << (6 - t);
        #pragma unroll
        for (int idx = size-1; idx >= 0; --idx){
            const int src  = idx >> 1;
            const int bsel = (idx & 1) ^ ((idx >> 1) & 1);
            float ar = vr[q][bsel], ai = vi[q][bsel];
            float nr = sr[src]*ar - si[src]*ai;
            float ni = sr[src]*ai + si[src]*ar;
            sr[idx] = nr; si[idx] = ni;
        }
    }
    // state = H' * LP(lane, j0)
    #pragma unroll
    for (int j = 0; j < 64; ++j){
        float br = (j & 1) ? lp1r : lp0r;
        float bi = (j & 1) ? lp1i : lp0i;
        float nr = sr[j]*br - si[j]*bi;
        float ni = sr[j]*bi + si[j]*br;
        sr[j] = nr; si[j] = ni;
    }

    // Layer-1 rotations, wires 0..5: in-lane
    inlane_gate<0>(sr, si, Gm + (12+0)*8);
    inlane_gate<1>(sr, si, Gm + (12+1)*8);
    inlane_gate<2>(sr, si, Gm + (12+2)*8);
    inlane_gate<3>(sr, si, Gm + (12+3)*8);
    inlane_gate<4>(sr, si, Gm + (12+4)*8);
    inlane_gate<5>(sr, si, Gm + (12+5)*8);

    // Wires 6..11: cross-lane pairs via shfl_xor
    #pragma unroll 1
    for (int w = 6; w < 12; ++w){
        const float* g = Gm + (12+w)*8;
        const int shift = 11 - w;
        const int xm = 1 << shift;
        const int myBit = (lane >> shift) & 1;
        float g00r=g[0], g00i=g[1], g01r=g[2], g01i=g[3];
        float g10r=g[4], g10i=g[5], g11r=g[6], g11i=g[7];
        float gar = myBit ? g11r : g00r;
        float gai = myBit ? g11i : g00i;
        float gbr = myBit ? g10r : g01r;
        float gbi = myBit ? g10i : g01i;
        #pragma unroll
        for (int j = 0; j < 64; ++j){
            float orr = __shfl_xor(sr[j], xm);
            float oii = __shfl_xor(si[j], xm);
            float nr = gar*sr[j] - gai*si[j] + gbr*orr - gbi*oii;
            float ni = gar*si[j] + gai*sr[j] + gbr*oii + gbi*orr;
            sr[j] = nr; si[j] = ni;
        }
    }

    // Measurement: <Z_w> = sum_k |s[k]|^2 * (-1)^{parity(k >> (11-w))}
    float s0=0.f,s1=0.f,s2=0.f,s3=0.f,s4=0.f,s5=0.f;
    #pragma unroll
    for (int j = 0; j < 64; ++j){
        float p = sr[j]*sr[j] + si[j]*si[j];
        s0 += (__builtin_popcount((unsigned)(j>>5)) & 1) ? -p : p;
        s1 += (__builtin_popcount((unsigned)(j>>4)) & 1) ? -p : p;
        s2 += (__builtin_popcount((unsigned)(j>>3)) & 1) ? -p : p;
        s3 += (__builtin_popcount((unsigned)(j>>2)) & 1) ? -p : p;
        s4 += (__builtin_popcount((unsigned)(j>>1)) & 1) ? -p : p;
        s5 += (__builtin_popcount((unsigned)(j   )) & 1) ? -p : p;
    }
    const float T = s5;   // full-j-parity signed sum, shared by wires 6..11
    float r0=s0, r1=s1, r2=s2, r3=s3, r4=s4, r5=s5;
    float r6  = (__builtin_popcount((unsigned)(lane>>5)) & 1) ? -T : T;
    float r7  = (__builtin_popcount((unsigned)(lane>>4)) & 1) ? -T : T;
    float r8  = (__builtin_popcount((unsigned)(lane>>3)) & 1) ? -T : T;
    float r9  = (__builtin_popcount((unsigned)(lane>>2)) & 1) ? -T : T;
    float r10 = (__builtin_popcount((unsigned)(lane>>1)) & 1) ? -T : T;
    float r11 = (__builtin_popcount((unsigned)(lane   )) & 1) ? -T : T;

    #pragma unroll
    for (int d = 1; d < 64; d <<= 1){
        r0  += __shfl_xor(r0,  d);
        r1  += __shfl_xor(r1,  d);
        r2  += __shfl_xor(r2,  d);
        r3  += __shfl_xor(r3,  d);
        r4  += __shfl_xor(r4,  d);
        r5  += __shfl_xor(r5,  d);
        r6  += __shfl_xor(r6,  d);
        r7  += __shfl_xor(r7,  d);
        r8  += __shfl_xor(r8,  d);
        r9  += __shfl_xor(r9,  d);
        r10 += __shfl_xor(r10, d);
        r11 += __shfl_xor(r11, d);
    }
    if (lane == 0){
        float* o = out + (size_t)b * NQ;
        o[0]=r0; o[1]=r1; o[2]=r2; o[3]=r3; o[4]=r4; o[5]=r5;
        o[6]=r6; o[7]=r7; o[8]=r8; o[9]=r9; o[10]=r10; o[11]=r11;
    }
}

extern "C" void kernel_launch(void* const* d_in, const int* in_sizes, int n_in,
                              void* d_out, int out_size, void* d_ws, size_t ws_size,
                              hipStream_t stream){
    const float* x   = (const float*)d_in[0];
    const float* wts = (const float*)d_in[1];
    float* out = (float*)d_out;
    float* gbuf = (float*)d_ws;           // 24 gates * 8 floats = 768 B
    const int B = in_sizes[0] / NQ;

    precompute_gates<<<1, 64, 0, stream>>>(wts, gbuf);
    qsim<<<(B + 3) / 4, 256, 0, stream>>>(x, gbuf, out, B);
}

// Round 3
// 108.565 us; speedup vs baseline: 8.9721x; 2.4530x over previous
//
#include <hip/hip_runtime.h>

#define NQ 12

typedef float f2 __attribute__((ext_vector_type(2)));

struct C2 { float r, i; };
__device__ __forceinline__ C2 cmul(C2 a, C2 b){ return C2{a.r*b.r - a.i*b.i, a.r*b.i + a.i*b.r}; }
__device__ __forceinline__ C2 cadd(C2 a, C2 b){ return C2{a.r + b.r, a.i + b.i}; }

// Precompute the 24 fused per-wire unitaries G = RZ(c) * RY(b) * RX(a)
// (layer-major: t = layer*12 + wire), stored as 8 floats each in d_ws.
__global__ void precompute_gates(const float* __restrict__ wts, float* __restrict__ gout){
    int t = threadIdx.x;
    if (t >= 2*NQ) return;
    float a = wts[3*t], bb = wts[3*t+1], c = wts[3*t+2];
    float sa, ca, sb, cb, sc, cc;
    sincosf(0.5f*a,  &sa, &ca);
    sincosf(0.5f*bb, &sb, &cb);
    sincosf(0.5f*c,  &sc, &cc);
    C2 rx00{ca,0.f}, rx01{0.f,-sa}, rx10{0.f,-sa}, rx11{ca,0.f};
    C2 ry00{cb,0.f}, ry01{-sb,0.f}, ry10{sb,0.f}, ry11{cb,0.f};
    C2 m00 = cadd(cmul(ry00,rx00), cmul(ry01,rx10));
    C2 m01 = cadd(cmul(ry00,rx01), cmul(ry01,rx11));
    C2 m10 = cadd(cmul(ry10,rx00), cmul(ry11,rx10));
    C2 m11 = cadd(cmul(ry10,rx01), cmul(ry11,rx11));
    C2 e0{cc,-sc}, e1{cc,sc};
    C2 g00 = cmul(e0,m00), g01 = cmul(e0,m01);
    C2 g10 = cmul(e1,m10), g11 = cmul(e1,m11);
    float* o = gout + t*8;
    o[0]=g00.r; o[1]=g00.i; o[2]=g01.r; o[3]=g01.i;
    o[4]=g10.r; o[5]=g10.i; o[6]=g11.r; o[7]=g11.i;
}

// Packed in-lane gate for layer-1 wires 0..4 on the 32 float2-slots.
// Original slot pairs (j0, j0+D), D = 2^(5-W) >= 2 -> packed pairs
// (m0, m0+Dp), Dp = D/2, identical math per half.
template<int W>
__device__ __forceinline__ void inlane_gateP(f2 (&sr)[32], f2 (&si)[32], const float* __restrict__ g){
    float g00r=g[0], g00i=g[1], g01r=g[2], g01i=g[3];
    float g10r=g[4], g10i=g[5], g11r=g[6], g11i=g[7];
    constexpr int Dp = 1 << (4 - W);
    #pragma unroll
    for (int p = 0; p < 16; ++p){
        const int m0 = ((p & ~(Dp-1)) << 1) | (p & (Dp-1));
        const int m1 = m0 + Dp;
        f2 a0r=sr[m0], a0i=si[m0], a1r=sr[m1], a1i=si[m1];
        sr[m0] = g00r*a0r - g00i*a0i + g01r*a1r - g01i*a1i;
        si[m0] = g00r*a0i + g00i*a0r + g01r*a1i + g01i*a1r;
        sr[m1] = g10r*a0r - g10i*a0i + g11r*a1r - g11i*a1i;
        si[m1] = g10r*a0i + g10i*a0r + g11r*a1i + g11i*a1r;
    }
}

// One wave simulates one batch element; 4096 amps = 64 lanes x 32 float2.
// State index k = 64*j + lane; slot j = wires 0..5 (j = 2m + half),
// lane bits = wires 6..11. Layer-0 CNOT chain folded as gray-code build;
// layer-1 CNOT chain folded into measurement parities. All slot math is
// elementwise across j -> packed f32 (v_pk_fma_f32) via ext_vector float2.
__global__ __launch_bounds__(256, 1)
void qsim(const float* __restrict__ x, const float* __restrict__ Gm,
          float* __restrict__ out, int B){
    const int lane = threadIdx.x & 63;
    const int wid  = threadIdx.x >> 6;
    const int b    = blockIdx.x * 4 + wid;
    if (b >= B) return;
    const float* xp = x + (size_t)b * NQ;

    // v_w = G0_w * [cos(x/2), sin(x/2)]^T
    float vr[12][2], vi[12][2];
    #pragma unroll
    for (int w = 0; w < 12; ++w){
        float sx, cx;
        __sincosf(0.5f * xp[w], &sx, &cx);
        const float* g = Gm + w*8;
        vr[w][0] = g[0]*cx + g[2]*sx;
        vi[w][0] = g[1]*cx + g[3]*sx;
        vr[w][1] = g[4]*cx + g[6]*sx;
        vi[w][1] = g[5]*cx + g[7]*sx;
    }

    // Low-product over wires 7..11 from gray bits of lane
    float lpr = 1.f, lpi = 0.f;
    #pragma unroll
    for (int m = 0; m <= 4; ++m){
        const int w = 11 - m;
        int bit = ((lane >> m) ^ (lane >> (m+1))) & 1;
        float ar = bit ? vr[w][1] : vr[w][0];
        float ai = bit ? vi[w][1] : vi[w][0];
        float nr = lpr*ar - lpi*ai;
        float ni = lpr*ai + lpi*ar;
        lpr = nr; lpi = ni;
    }
    // wire-6 gray bit = l5 ^ j0 -> two lp variants by slot parity j0
    const int l5 = (lane >> 5) & 1;
    float a6r0 = l5 ? vr[6][1] : vr[6][0];
    float a6i0 = l5 ? vi[6][1] : vi[6][0];
    float a6r1 = l5 ? vr[6][0] : vr[6][1];
    float a6i1 = l5 ? vi[6][0] : vi[6][1];
    float lp0r = lpr*a6r0 - lpi*a6i0, lp0i = lpr*a6i0 + lpi*a6r0;
    float lp1r = lpr*a6r1 - lpi*a6i1, lp1i = lpr*a6i1 + lpi*a6r1;

    // Combined constants for the wire-5 doubling stage fused with LP:
    // for packed slot m (j = 2m -> x, 2m+1 -> y), b = m&1:
    //   c_b = { v5[b]*lp0 , v5[1-b]*lp1 }   (complex, per half)
    f2 c0r = f2{ vr[5][0]*lp0r - vi[5][0]*lp0i,  vr[5][1]*lp1r - vi[5][1]*lp1i };
    f2 c0i = f2{ vr[5][0]*lp0i + vi[5][0]*lp0r,  vr[5][1]*lp1i + vi[5][1]*lp1r };
    f2 c1r = f2{ vr[5][1]*lp0r - vi[5][1]*lp0i,  vr[5][0]*lp1r - vi[5][0]*lp1i };
    f2 c1i = f2{ vr[5][1]*lp0i + vi[5][1]*lp0r,  vr[5][0]*lp1i + vi[5][0]*lp1r };

    // State build. Phase 1: scalar gray doubling over wires 0..4 producing
    // h[0..31], stored at sr[e>>1][e&1]. Phase 2: packed wire-5 stage + LP
    // fold, in place, descending m (reads h[m] before it is clobbered).
    f2 sr[32], si[32];
    sr[0][0] = vr[0][0]; si[0][0] = vi[0][0];
    sr[0][1] = vr[0][1]; si[0][1] = vi[0][1];
    #pragma unroll
    for (int t = 4; t >= 1; --t){
        const int q = 5 - t;            // wire 1..4
        const int size = 1 << (6 - t);  // 4,8,16,32
        #pragma unroll
        for (int idx = size-1; idx >= 0; --idx){
            const int src  = idx >> 1;
            const int bsel = (idx & 1) ^ ((idx >> 1) & 1);
            float hr = sr[src>>1][src&1], hi = si[src>>1][src&1];
            float ar = vr[q][bsel], ai = vi[q][bsel];
            sr[idx>>1][idx&1] = hr*ar - hi*ai;
            si[idx>>1][idx&1] = hr*ai + hi*ar;
        }
    }
    #pragma unroll
    for (int m = 31; m >= 0; --m){
        float hr = sr[m>>1][m&1], hi = si[m>>1][m&1];
        f2 cr = (m & 1) ? c1r : c0r;
        f2 ci = (m & 1) ? c1i : c0i;
        sr[m] = hr*cr - hi*ci;
        si[m] = hr*ci + hi*cr;
    }

    // Layer-1 in-lane gates, wires 0..4 (packed pairs)
    const float* G1 = Gm + 12*8;
    inlane_gateP<0>(sr, si, G1 + 0*8);
    inlane_gateP<1>(sr, si, G1 + 1*8);
    inlane_gateP<2>(sr, si, G1 + 2*8);
    inlane_gateP<3>(sr, si, G1 + 3*8);
    inlane_gateP<4>(sr, si, G1 + 4*8);

    // Wire 5: pair is within one float2 -> diag/off-diag packed constants + swap
    {
        const float* g = G1 + 5*8;
        f2 vdr = f2{g[0], g[6]}, vdi = f2{g[1], g[7]};   // {g00, g11}
        f2 vor_= f2{g[2], g[4]}, voi = f2{g[3], g[5]};   // {g01, g10}
        #pragma unroll
        for (int m = 0; m < 32; ++m){
            f2 ar = sr[m], ai = si[m];
            f2 ars = __builtin_shufflevector(ar, ar, 1, 0);
            f2 ais = __builtin_shufflevector(ai, ai, 1, 0);
            sr[m] = vdr*ar - vdi*ai + vor_*ars - voi*ais;
            si[m] = vdr*ai + vdi*ar + vor_*ais + voi*ars;
        }
    }

    // Wires 6..11: cross-lane pairs via shfl_xor (fully unrolled)
    #pragma unroll
    for (int w = 6; w < 12; ++w){
        const float* g = G1 + w*8;
        const int shift = 11 - w;
        const int xm = 1 << shift;
        const int myBit = (lane >> shift) & 1;
        float gar = myBit ? g[6] : g[0];
        float gai = myBit ? g[7] : g[1];
        float gbr = myBit ? g[4] : g[2];
        float gbi = myBit ? g[5] : g[3];
        #pragma unroll
        for (int m = 0; m < 32; ++m){
            f2 s_r = sr[m], s_i = si[m];
            f2 o_r, o_i;
            o_r.x = __shfl_xor(s_r.x, xm);
            o_r.y = __shfl_xor(s_r.y, xm);
            o_i.x = __shfl_xor(s_i.x, xm);
            o_i.y = __shfl_xor(s_i.y, xm);
            sr[m] = gar*s_r - gai*s_i + gbr*o_r - gbi*o_i;
            si[m] = gar*s_i + gai*s_r + gbr*o_i + gbi*o_r;
        }
    }

    // Measurement: packed signed accumulators t_k (sign = parity(m>>k)).
    // j = 2m + half: wire5 sign = parity(m)^half; wires 0..4 -> parity(m>>k).
    f2 t0 = f2{0.f,0.f}, t1 = f2{0.f,0.f}, t2 = f2{0.f,0.f},
       t3 = f2{0.f,0.f}, t4 = f2{0.f,0.f};
    #pragma unroll
    for (int m = 0; m < 32; ++m){
        f2 p = sr[m]*sr[m] + si[m]*si[m];
        t0 += (__builtin_popcount((unsigned)(m   )) & 1) ? -p : p;
        t1 += (__builtin_popcount((unsigned)(m>>1)) & 1) ? -p : p;
        t2 += (__builtin_popcount((unsigned)(m>>2)) & 1) ? -p : p;
        t3 += (__builtin_popcount((unsigned)(m>>3)) & 1) ? -p : p;
        t4 += (__builtin_popcount((unsigned)(m>>4)) & 1) ? -p : p;
    }
    float s0 = t4.x + t4.y;   // wire 0: parity(j>>5) = parity(m>>4)
    float s1 = t3.x + t3.y;
    float s2 = t2.x + t2.y;
    float s3 = t1.x + t1.y;
    float s4 = t0.x + t0.y;   // wire 4: parity(j>>1) = parity(m)
    float s5 = t0.x - t0.y;   // wire 5: parity(j) = parity(m)^half

    const float T = s5;       // full-parity signed sum, shared by wires 6..11
    float r0=s0, r1=s1, r2=s2, r3=s3, r4=s4, r5=s5;
    float r6  = (__builtin_popcount((unsigned)(lane>>5)) & 1) ? -T : T;
    float r7  = (__builtin_popcount((unsigned)(lane>>4)) & 1) ? -T : T;
    float r8  = (__builtin_popcount((unsigned)(lane>>3)) & 1) ? -T : T;
    float r9  = (__builtin_popcount((unsigned)(lane>>2)) & 1) ? -T : T;
    float r10 = (__builtin_popcount((unsigned)(lane>>1)) & 1) ? -T : T;
    float r11 = (__builtin_popcount((unsigned)(lane   )) & 1) ? -T : T;

    #pragma unroll
    for (int d = 1; d < 64; d <<= 1){
        r0  += __shfl_xor(r0,  d);
        r1  += __shfl_xor(r1,  d);
        r2  += __shfl_xor(r2,  d);
        r3  += __shfl_xor(r3,  d);
        r4  += __shfl_xor(r4,  d);
        r5  += __shfl_xor(r5,  d);
        r6  += __shfl_xor(r6,  d);
        r7  += __shfl_xor(r7,  d);
        r8  += __shfl_xor(r8,  d);
        r9  += __shfl_xor(r9,  d);
        r10 += __shfl_xor(r10, d);
        r11 += __shfl_xor(r11, d);
    }
    if (lane == 0){
        float* o = out + (size_t)b * NQ;
        o[0]=r0; o[1]=r1; o[2]=r2; o[3]=r3; o[4]=r4; o[5]=r5;
        o[6]=r6; o[7]=r7; o[8]=r8; o[9]=r9; o[10]=r10; o[11]=r11;
    }
}

extern "C" void kernel_launch(void* const* d_in, const int* in_sizes, int n_in,
                              void* d_out, int out_size, void* d_ws, size_t ws_size,
                              hipStream_t stream){
    const float* x   = (const float*)d_in[0];
    const float* wts = (const float*)d_in[1];
    float* out = (float*)d_out;
    float* gbuf = (float*)d_ws;           // 24 gates * 8 floats = 768 B
    const int B = in_sizes[0] / NQ;

    precompute_gates<<<1, 64, 0, stream>>>(wts, gbuf);
    qsim<<<(B + 3) / 4, 256, 0, stream>>>(x, gbuf, out, B);
}

// Round 4
// 105.048 us; speedup vs baseline: 9.2725x; 1.0335x over previous
//
#include <hip/hip_runtime.h>

#define NQ 12

typedef float f2 __attribute__((ext_vector_type(2)));

struct C2 { float r, i; };
__device__ __forceinline__ C2 cmul(C2 a, C2 b){ return C2{a.r*b.r - a.i*b.i, a.r*b.i + a.i*b.r}; }
__device__ __forceinline__ C2 cadd(C2 a, C2 b){ return C2{a.r + b.r, a.i + b.i}; }

// Precompute the 24 fused per-wire unitaries G = RZ(c) * RY(b) * RX(a)
// (layer-major: t = layer*12 + wire), stored as 8 floats each in d_ws.
__global__ void precompute_gates(const float* __restrict__ wts, float* __restrict__ gout){
    int t = threadIdx.x;
    if (t >= 2*NQ) return;
    float a = wts[3*t], bb = wts[3*t+1], c = wts[3*t+2];
    float sa, ca, sb, cb, sc, cc;
    sincosf(0.5f*a,  &sa, &ca);
    sincosf(0.5f*bb, &sb, &cb);
    sincosf(0.5f*c,  &sc, &cc);
    C2 rx00{ca,0.f}, rx01{0.f,-sa}, rx10{0.f,-sa}, rx11{ca,0.f};
    C2 ry00{cb,0.f}, ry01{-sb,0.f}, ry10{sb,0.f}, ry11{cb,0.f};
    C2 m00 = cadd(cmul(ry00,rx00), cmul(ry01,rx10));
    C2 m01 = cadd(cmul(ry00,rx01), cmul(ry01,rx11));
    C2 m10 = cadd(cmul(ry10,rx00), cmul(ry11,rx10));
    C2 m11 = cadd(cmul(ry10,rx01), cmul(ry11,rx11));
    C2 e0{cc,-sc}, e1{cc,sc};
    C2 g00 = cmul(e0,m00), g01 = cmul(e0,m01);
    C2 g10 = cmul(e1,m10), g11 = cmul(e1,m11);
    float* o = gout + t*8;
    o[0]=g00.r; o[1]=g00.i; o[2]=g01.r; o[3]=g01.i;
    o[4]=g10.r; o[5]=g10.i; o[6]=g11.r; o[7]=g11.i;
}

// Packed in-lane gate for layer-1 wires 0..4 on the 32 float2-slots.
// Whole-vector accesses only; all indices compile-time after unroll.
template<int W>
__device__ __forceinline__ void inlane_gateP(f2 (&sr)[32], f2 (&si)[32], const float* __restrict__ g){
    float g00r=g[0], g00i=g[1], g01r=g[2], g01i=g[3];
    float g10r=g[4], g10i=g[5], g11r=g[6], g11i=g[7];
    constexpr int Dp = 1 << (4 - W);
    #pragma unroll
    for (int p = 0; p < 16; ++p){
        const int m0 = ((p & ~(Dp-1)) << 1) | (p & (Dp-1));
        const int m1 = m0 + Dp;
        f2 a0r=sr[m0], a0i=si[m0], a1r=sr[m1], a1i=si[m1];
        sr[m0] = g00r*a0r - g00i*a0i + g01r*a1r - g01i*a1i;
        si[m0] = g00r*a0i + g00i*a0r + g01r*a1i + g01i*a1r;
        sr[m1] = g10r*a0r - g10i*a0i + g11r*a1r - g11i*a1i;
        si[m1] = g10r*a0i + g10i*a0r + g11r*a1i + g11i*a1r;
    }
}

// One wave simulates one batch element; 4096 amps = 64 lanes x 32 float2.
// State index k = 64*j + lane; slot j = 2m + half, lane bits = wires 6..11.
// Layer-0 CNOT chain folded as gray-code build; layer-1 CNOT chain folded
// into measurement parities. Packed f32 (v_pk_fma_f32) via ext_vector f2.
//
// REGISTER DISCIPLINE (round-3 lesson): the f2 state arrays are accessed
// ONLY as whole vectors with literal indices. The gray-code build uses
// separate scalar hr/hi arrays with explicit literal-bound stage loops —
// the previous nested dependent-bound loops + mixed component/vector
// writes to one alloca defeated SROA and spilled the state (VGPR=108,
// 93 MB scratch writes).
__global__ __launch_bounds__(256, 1)
void qsim(const float* __restrict__ x, const float* __restrict__ Gm,
          float* __restrict__ out, int B){
    const int lane = threadIdx.x & 63;
    const int wid  = threadIdx.x >> 6;
    const int b    = blockIdx.x * 4 + wid;
    if (b >= B) return;
    const float* xp = x + (size_t)b * NQ;

    // v_w = G0_w * [cos(x/2), sin(x/2)]^T
    float vr[12][2], vi[12][2];
    #pragma unroll
    for (int w = 0; w < 12; ++w){
        float sx, cx;
        __sincosf(0.5f * xp[w], &sx, &cx);
        const float* g = Gm + w*8;
        vr[w][0] = g[0]*cx + g[2]*sx;
        vi[w][0] = g[1]*cx + g[3]*sx;
        vr[w][1] = g[4]*cx + g[6]*sx;
        vi[w][1] = g[5]*cx + g[7]*sx;
    }

    // Low-product over wires 7..11 from gray bits of lane
    float lpr = 1.f, lpi = 0.f;
    #pragma unroll
    for (int m = 0; m <= 4; ++m){
        const int w = 11 - m;
        int bit = ((lane >> m) ^ (lane >> (m+1))) & 1;
        float ar = bit ? vr[w][1] : vr[w][0];
        float ai = bit ? vi[w][1] : vi[w][0];
        float nr = lpr*ar - lpi*ai;
        float ni = lpr*ai + lpi*ar;
        lpr = nr; lpi = ni;
    }
    // wire-6 gray bit = l5 ^ j0 -> two lp variants by slot parity j0
    const int l5 = (lane >> 5) & 1;
    float a6r0 = l5 ? vr[6][1] : vr[6][0];
    float a6i0 = l5 ? vi[6][1] : vi[6][0];
    float a6r1 = l5 ? vr[6][0] : vr[6][1];
    float a6i1 = l5 ? vi[6][0] : vi[6][1];
    float lp0r = lpr*a6r0 - lpi*a6i0, lp0i = lpr*a6i0 + lpi*a6r0;
    float lp1r = lpr*a6r1 - lpi*a6i1, lp1i = lpr*a6i1 + lpi*a6r1;

    // Combined constants for the wire-5 stage fused with LP:
    //   m even: c0 = { v5[0]*lp0 , v5[1]*lp1 }
    //   m odd : c1 = { v5[1]*lp0 , v5[0]*lp1 }
    f2 c0r = f2{ vr[5][0]*lp0r - vi[5][0]*lp0i,  vr[5][1]*lp1r - vi[5][1]*lp1i };
    f2 c0i = f2{ vr[5][0]*lp0i + vi[5][0]*lp0r,  vr[5][1]*lp1i + vi[5][1]*lp1r };
    f2 c1r = f2{ vr[5][1]*lp0r - vi[5][1]*lp0i,  vr[5][0]*lp1r - vi[5][0]*lp1i };
    f2 c1i = f2{ vr[5][1]*lp0i + vi[5][1]*lp0r,  vr[5][0]*lp1i + vi[5][0]*lp1r };

    // Phase 1: scalar gray-code doubling over wires 0..4 -> hr/hi[0..31].
    // Explicit stages, literal bounds, in-place descending (src = idx>>1).
    float hr[32], hi[32];
    hr[0] = vr[0][0]; hi[0] = vi[0][0];
    hr[1] = vr[0][1]; hi[1] = vi[0][1];
    #pragma unroll
    for (int idx = 3; idx >= 0; --idx){      // wire 1
        const int bsel = (idx & 1) ^ ((idx >> 1) & 1);
        float ar = vr[1][bsel], ai = vi[1][bsel];
        float pr = hr[idx>>1], pi = hi[idx>>1];
        hr[idx] = pr*ar - pi*ai; hi[idx] = pr*ai + pi*ar;
    }
    #pragma unroll
    for (int idx = 7; idx >= 0; --idx){      // wire 2
        const int bsel = (idx & 1) ^ ((idx >> 1) & 1);
        float ar = vr[2][bsel], ai = vi[2][bsel];
        float pr = hr[idx>>1], pi = hi[idx>>1];
        hr[idx] = pr*ar - pi*ai; hi[idx] = pr*ai + pi*ar;
    }
    #pragma unroll
    for (int idx = 15; idx >= 0; --idx){     // wire 3
        const int bsel = (idx & 1) ^ ((idx >> 1) & 1);
        float ar = vr[3][bsel], ai = vi[3][bsel];
        float pr = hr[idx>>1], pi = hi[idx>>1];
        hr[idx] = pr*ar - pi*ai; hi[idx] = pr*ai + pi*ar;
    }
    #pragma unroll
    for (int idx = 31; idx >= 0; --idx){     // wire 4
        const int bsel = (idx & 1) ^ ((idx >> 1) & 1);
        float ar = vr[4][bsel], ai = vi[4][bsel];
        float pr = hr[idx>>1], pi = hi[idx>>1];
        hr[idx] = pr*ar - pi*ai; hi[idx] = pr*ai + pi*ar;
    }

    // Phase 2: packed wire-5 + LP fold; whole-vector writes only.
    f2 sr[32], si[32];
    #pragma unroll
    for (int m = 0; m < 32; ++m){
        f2 cr = (m & 1) ? c1r : c0r;
        f2 ci = (m & 1) ? c1i : c0i;
        sr[m] = hr[m]*cr - hi[m]*ci;
        si[m] = hr[m]*ci + hi[m]*cr;
    }

    // Layer-1 in-lane gates, wires 0..4 (packed pairs)
    const float* G1 = Gm + 12*8;
    inlane_gateP<0>(sr, si, G1 + 0*8);
    inlane_gateP<1>(sr, si, G1 + 1*8);
    inlane_gateP<2>(sr, si, G1 + 2*8);
    inlane_gateP<3>(sr, si, G1 + 3*8);
    inlane_gateP<4>(sr, si, G1 + 4*8);

    // Wire 5: pair within one float2 -> diag/off-diag packed constants + swap
    {
        const float* g = G1 + 5*8;
        f2 vdr = f2{g[0], g[6]}, vdi = f2{g[1], g[7]};   // {g00, g11}
        f2 vor_= f2{g[2], g[4]}, voi = f2{g[3], g[5]};   // {g01, g10}
        #pragma unroll
        for (int m = 0; m < 32; ++m){
            f2 ar = sr[m], ai = si[m];
            f2 ars = __builtin_shufflevector(ar, ar, 1, 0);
            f2 ais = __builtin_shufflevector(ai, ai, 1, 0);
            sr[m] = vdr*ar - vdi*ai + vor_*ars - voi*ais;
            si[m] = vdr*ai + vdi*ar + vor_*ais + voi*ars;
        }
    }

    // Wires 6..11: cross-lane pairs via shfl_xor (fully unrolled)
    #pragma unroll
    for (int w = 6; w < 12; ++w){
        const float* g = G1 + w*8;
        const int shift = 11 - w;
        const int xm = 1 << shift;
        const int myBit = (lane >> shift) & 1;
        float gar = myBit ? g[6] : g[0];
        float gai = myBit ? g[7] : g[1];
        float gbr = myBit ? g[4] : g[2];
        float gbi = myBit ? g[5] : g[3];
        #pragma unroll
        for (int m = 0; m < 32; ++m){
            f2 s_r = sr[m], s_i = si[m];
            f2 o_r, o_i;
            o_r.x = __shfl_xor(s_r.x, xm);
            o_r.y = __shfl_xor(s_r.y, xm);
            o_i.x = __shfl_xor(s_i.x, xm);
            o_i.y = __shfl_xor(s_i.y, xm);
            sr[m] = gar*s_r - gai*s_i + gbr*o_r - gbi*o_i;
            si[m] = gar*s_i + gai*s_r + gbr*o_i + gbi*o_r;
        }
    }

    // Measurement: packed signed accumulators t_k (sign = parity(m>>k)).
    f2 t0 = f2{0.f,0.f}, t1 = f2{0.f,0.f}, t2 = f2{0.f,0.f},
       t3 = f2{0.f,0.f}, t4 = f2{0.f,0.f};
    #pragma unroll
    for (int m = 0; m < 32; ++m){
        f2 p = sr[m]*sr[m] + si[m]*si[m];
        t0 += (__builtin_popcount((unsigned)(m   )) & 1) ? -p : p;
        t1 += (__builtin_popcount((unsigned)(m>>1)) & 1) ? -p : p;
        t2 += (__builtin_popcount((unsigned)(m>>2)) & 1) ? -p : p;
        t3 += (__builtin_popcount((unsigned)(m>>3)) & 1) ? -p : p;
        t4 += (__builtin_popcount((unsigned)(m>>4)) & 1) ? -p : p;
    }
    float s0 = t4.x + t4.y;   // wire 0: parity(m>>4)
    float s1 = t3.x + t3.y;
    float s2 = t2.x + t2.y;
    float s3 = t1.x + t1.y;
    float s4 = t0.x + t0.y;   // wire 4: parity(m)
    float s5 = t0.x - t0.y;   // wire 5: parity(m)^half

    const float T = s5;       // full-parity signed sum, shared by wires 6..11
    float r0=s0, r1=s1, r2=s2, r3=s3, r4=s4, r5=s5;
    float r6  = (__builtin_popcount((unsigned)(lane>>5)) & 1) ? -T : T;
    float r7  = (__builtin_popcount((unsigned)(lane>>4)) & 1) ? -T : T;
    float r8  = (__builtin_popcount((unsigned)(lane>>3)) & 1) ? -T : T;
    float r9  = (__builtin_popcount((unsigned)(lane>>2)) & 1) ? -T : T;
    float r10 = (__builtin_popcount((unsigned)(lane>>1)) & 1) ? -T : T;
    float r11 = (__builtin_popcount((unsigned)(lane   )) & 1) ? -T : T;

    #pragma unroll
    for (int d = 1; d < 64; d <<= 1){
        r0  += __shfl_xor(r0,  d);
        r1  += __shfl_xor(r1,  d);
        r2  += __shfl_xor(r2,  d);
        r3  += __shfl_xor(r3,  d);
        r4  += __shfl_xor(r4,  d);
        r5  += __shfl_xor(r5,  d);
        r6  += __shfl_xor(r6,  d);
        r7  += __shfl_xor(r7,  d);
        r8  += __shfl_xor(r8,  d);
        r9  += __shfl_xor(r9,  d);
        r10 += __shfl_xor(r10, d);
        r11 += __shfl_xor(r11, d);
    }
    if (lane == 0){
        float* o = out + (size_t)b * NQ;
        o[0]=r0; o[1]=r1; o[2]=r2; o[3]=r3; o[4]=r4; o[5]=r5;
        o[6]=r6; o[7]=r7; o[8]=r8; o[9]=r9; o[10]=r10; o[11]=r11;
    }
}

extern "C" void kernel_launch(void* const* d_in, const int* in_sizes, int n_in,
                              void* d_out, int out_size, void* d_ws, size_t ws_size,
                              hipStream_t stream){
    const float* x   = (const float*)d_in[0];
    const float* wts = (const float*)d_in[1];
    float* out = (float*)d_out;
    float* gbuf = (float*)d_ws;           // 24 gates * 8 floats = 768 B
    const int B = in_sizes[0] / NQ;

    precompute_gates<<<1, 64, 0, stream>>>(wts, gbuf);
    qsim<<<(B + 3) / 4, 256, 0, stream>>>(x, gbuf, out, B);
}

// Round 5
// 97.613 us; speedup vs baseline: 9.9787x; 1.0762x over previous
//
#include <hip/hip_runtime.h>

#define NQ 12

typedef float f2 __attribute__((ext_vector_type(2)));

struct C2 { float r, i; };
__device__ __forceinline__ C2 cmul(C2 a, C2 b){ return C2{a.r*b.r - a.i*b.i, a.r*b.i + a.i*b.r}; }
__device__ __forceinline__ C2 cadd(C2 a, C2 b){ return C2{a.r + b.r, a.i + b.i}; }

// Precompute the 24 fused per-wire unitaries G = RZ(c) * RY(b) * RX(a)
// (layer-major: t = layer*12 + wire), stored as 8 floats each in d_ws.
__global__ void precompute_gates(const float* __restrict__ wts, float* __restrict__ gout){
    int t = threadIdx.x;
    if (t >= 2*NQ) return;
    float a = wts[3*t], bb = wts[3*t+1], c = wts[3*t+2];
    float sa, ca, sb, cb, sc, cc;
    sincosf(0.5f*a,  &sa, &ca);
    sincosf(0.5f*bb, &sb, &cb);
    sincosf(0.5f*c,  &sc, &cc);
    C2 rx00{ca,0.f}, rx01{0.f,-sa}, rx10{0.f,-sa}, rx11{ca,0.f};
    C2 ry00{cb,0.f}, ry01{-sb,0.f}, ry10{sb,0.f}, ry11{cb,0.f};
    C2 m00 = cadd(cmul(ry00,rx00), cmul(ry01,rx10));
    C2 m01 = cadd(cmul(ry00,rx01), cmul(ry01,rx11));
    C2 m10 = cadd(cmul(ry10,rx00), cmul(ry11,rx10));
    C2 m11 = cadd(cmul(ry10,rx01), cmul(ry11,rx11));
    C2 e0{cc,-sc}, e1{cc,sc};
    C2 g00 = cmul(e0,m00), g01 = cmul(e0,m01);
    C2 g10 = cmul(e1,m10), g11 = cmul(e1,m11);
    float* o = gout + t*8;
    o[0]=g00.r; o[1]=g00.i; o[2]=g01.r; o[3]=g01.i;
    o[4]=g10.r; o[5]=g10.i; o[6]=g11.r; o[7]=g11.i;
}

// ---- macro machinery: the whole state lives in NAMED registers. ----
#define REP32(M) M(0) M(1) M(2) M(3) M(4) M(5) M(6) M(7) M(8) M(9) M(10) M(11) \
                 M(12) M(13) M(14) M(15) M(16) M(17) M(18) M(19) M(20) M(21) M(22) M(23) \
                 M(24) M(25) M(26) M(27) M(28) M(29) M(30) M(31)

// pair lists for in-lane gates on packed slots (wire W, Dp = 2^(4-W))
#define PAIRS_W0(M) M(0,16) M(1,17) M(2,18) M(3,19) M(4,20) M(5,21) M(6,22) M(7,23) \
                    M(8,24) M(9,25) M(10,26) M(11,27) M(12,28) M(13,29) M(14,30) M(15,31)
#define PAIRS_W1(M) M(0,8) M(1,9) M(2,10) M(3,11) M(4,12) M(5,13) M(6,14) M(7,15) \
                    M(16,24) M(17,25) M(18,26) M(19,27) M(20,28) M(21,29) M(22,30) M(23,31)
#define PAIRS_W2(M) M(0,4) M(1,5) M(2,6) M(3,7) M(8,12) M(9,13) M(10,14) M(11,15) \
                    M(16,20) M(17,21) M(18,22) M(19,23) M(24,28) M(25,29) M(26,30) M(27,31)
#define PAIRS_W3(M) M(0,2) M(1,3) M(4,6) M(5,7) M(8,10) M(9,11) M(12,14) M(13,15) \
                    M(16,18) M(17,19) M(20,22) M(21,23) M(24,26) M(25,27) M(28,30) M(29,31)
#define PAIRS_W4(M) M(0,1) M(2,3) M(4,5) M(6,7) M(8,9) M(10,11) M(12,13) M(14,15) \
                    M(16,17) M(18,19) M(20,21) M(22,23) M(24,25) M(26,27) M(28,29) M(30,31)

// One wave simulates one batch element; 4096 amps = 64 lanes x 32 packed f2.
// Slot j = 2m + half (wires 0..5), lane bits = wires 6..11. Layer-0 CNOT
// chain folded as gray-code build; layer-1 CNOT chain folded into the
// measurement parities.
// Rounds 3/4 lesson: hipcc failed to SROA-promote [32 x <2 x float>]
// allocas (VGPR=108, 94 MB scratch writes) no matter the access pattern.
// Fix: NO ARRAYS AT ALL — every state element is a named variable, all
// stage code macro-generated with literal indices.
__global__ __launch_bounds__(256, 1)
void qsim(const float* __restrict__ x, const float* __restrict__ Gm,
          float* __restrict__ out, int B){
    const int lane = threadIdx.x & 63;
    const int wid  = threadIdx.x >> 6;
    const int b    = blockIdx.x * 4 + wid;
    if (b >= B) return;
    const float* xp = x + (size_t)b * NQ;

    // v_w = G0_w * [cos(x/2), sin(x/2)]^T  -> named scalars
#define DECLV(w) float v##w##r0, v##w##i0, v##w##r1, v##w##i1;
    DECLV(0) DECLV(1) DECLV(2) DECLV(3) DECLV(4) DECLV(5)
    DECLV(6) DECLV(7) DECLV(8) DECLV(9) DECLV(10) DECLV(11)
#define LOADV(w) { float sx, cx; __sincosf(0.5f * xp[w], &sx, &cx); \
    const float* g = Gm + (w)*8; \
    v##w##r0 = g[0]*cx + g[2]*sx;  v##w##i0 = g[1]*cx + g[3]*sx; \
    v##w##r1 = g[4]*cx + g[6]*sx;  v##w##i1 = g[5]*cx + g[7]*sx; }
    LOADV(0) LOADV(1) LOADV(2) LOADV(3) LOADV(4) LOADV(5)
    LOADV(6) LOADV(7) LOADV(8) LOADV(9) LOADV(10) LOADV(11)

    // Low-product over wires 7..11 from gray bits of lane
    float lpr = 1.f, lpi = 0.f;
#define LPSTEP(m, w) { const int bit = ((lane >> (m)) ^ (lane >> ((m)+1))) & 1; \
    float ar = bit ? v##w##r1 : v##w##r0; float ai = bit ? v##w##i1 : v##w##i0; \
    float nr = lpr*ar - lpi*ai; float ni = lpr*ai + lpi*ar; lpr = nr; lpi = ni; }
    LPSTEP(0,11) LPSTEP(1,10) LPSTEP(2,9) LPSTEP(3,8) LPSTEP(4,7)

    // wire-6 gray bit = l5 ^ j0 -> two lp variants by slot parity j0
    const int l5 = (lane >> 5) & 1;
    float a6r0 = l5 ? v6r1 : v6r0;
    float a6i0 = l5 ? v6i1 : v6i0;
    float a6r1 = l5 ? v6r0 : v6r1;
    float a6i1 = l5 ? v6i0 : v6i1;
    float lp0r = lpr*a6r0 - lpi*a6i0, lp0i = lpr*a6i0 + lpi*a6r0;
    float lp1r = lpr*a6r1 - lpi*a6i1, lp1i = lpr*a6i1 + lpi*a6r1;

    // Combined constants for the wire-5 stage fused with LP:
    //   m even: c0 = { v5[0]*lp0 , v5[1]*lp1 } ; m odd: c1 = { v5[1]*lp0 , v5[0]*lp1 }
    f2 c0r = f2{ v5r0*lp0r - v5i0*lp0i,  v5r1*lp1r - v5i1*lp1i };
    f2 c0i = f2{ v5r0*lp0i + v5i0*lp0r,  v5r1*lp1i + v5i1*lp1r };
    f2 c1r = f2{ v5r1*lp0r - v5i1*lp0i,  v5r0*lp1r - v5i0*lp1i };
    f2 c1i = f2{ v5r1*lp0i + v5i1*lp0r,  v5r0*lp1i + v5i0*lp1r };

    // Phase 1: gray-code doubling over wires 0..4 -> named h0..h31 (complex).
#define DECL_H(m) float h##m##r, h##m##i;
    REP32(DECL_H)
    h0r = v0r0; h0i = v0i0;
    h1r = v0r1; h1i = v0i1;
#define HSTEP(w, idx, src) { const int B_ = ((idx)&1)^(((idx)>>1)&1); \
    float ar = B_ ? v##w##r1 : v##w##r0; float ai = B_ ? v##w##i1 : v##w##i0; \
    float pr = h##src##r, pi = h##src##i; \
    h##idx##r = pr*ar - pi*ai; h##idx##i = pr*ai + pi*ar; }
    // wire 1 (descending idx; src = idx>>1 read before overwrite)
    HSTEP(1,3,1) HSTEP(1,2,1) HSTEP(1,1,0) HSTEP(1,0,0)
    // wire 2
    HSTEP(2,7,3) HSTEP(2,6,3) HSTEP(2,5,2) HSTEP(2,4,2)
    HSTEP(2,3,1) HSTEP(2,2,1) HSTEP(2,1,0) HSTEP(2,0,0)
    // wire 3
    HSTEP(3,15,7) HSTEP(3,14,7) HSTEP(3,13,6) HSTEP(3,12,6)
    HSTEP(3,11,5) HSTEP(3,10,5) HSTEP(3,9,4)  HSTEP(3,8,4)
    HSTEP(3,7,3)  HSTEP(3,6,3)  HSTEP(3,5,2)  HSTEP(3,4,2)
    HSTEP(3,3,1)  HSTEP(3,2,1)  HSTEP(3,1,0)  HSTEP(3,0,0)
    // wire 4
    HSTEP(4,31,15) HSTEP(4,30,15) HSTEP(4,29,14) HSTEP(4,28,14)
    HSTEP(4,27,13) HSTEP(4,26,13) HSTEP(4,25,12) HSTEP(4,24,12)
    HSTEP(4,23,11) HSTEP(4,22,11) HSTEP(4,21,10) HSTEP(4,20,10)
    HSTEP(4,19,9)  HSTEP(4,18,9)  HSTEP(4,17,8)  HSTEP(4,16,8)
    HSTEP(4,15,7)  HSTEP(4,14,7)  HSTEP(4,13,6)  HSTEP(4,12,6)
    HSTEP(4,11,5)  HSTEP(4,10,5)  HSTEP(4,9,4)   HSTEP(4,8,4)
    HSTEP(4,7,3)   HSTEP(4,6,3)   HSTEP(4,5,2)   HSTEP(4,4,2)
    HSTEP(4,3,1)   HSTEP(4,2,1)   HSTEP(4,1,0)   HSTEP(4,0,0)

    // Phase 2: packed wire-5 + LP fold into named f2 state sr0..sr31 / si0..si31
#define DECL_S(m) f2 sr##m, si##m;
    REP32(DECL_S)
#define PH2(m) { f2 cr = ((m)&1) ? c1r : c0r; f2 ci = ((m)&1) ? c1i : c0i; \
    sr##m = h##m##r*cr - h##m##i*ci; si##m = h##m##r*ci + h##m##i*cr; }
    REP32(PH2)

    // Layer-1 in-lane gates, wires 0..4 (packed pairs)
    const float* G1 = Gm + 12*8;
#define GATE(m0, m1) { f2 a0r=sr##m0, a0i=si##m0, a1r=sr##m1, a1i=si##m1; \
    sr##m0 = g00r*a0r - g00i*a0i + g01r*a1r - g01i*a1i; \
    si##m0 = g00r*a0i + g00i*a0r + g01r*a1i + g01i*a1r; \
    sr##m1 = g10r*a0r - g10i*a0i + g11r*a1r - g11i*a1i; \
    si##m1 = g10r*a0i + g10i*a0r + g11r*a1i + g11i*a1r; }
#define GATE_STAGE(PAIRS, OFF) { const float* g = G1 + (OFF)*8; \
    float g00r=g[0], g00i=g[1], g01r=g[2], g01i=g[3]; \
    float g10r=g[4], g10i=g[5], g11r=g[6], g11i=g[7]; \
    PAIRS(GATE) }
    GATE_STAGE(PAIRS_W0, 0)
    GATE_STAGE(PAIRS_W1, 1)
    GATE_STAGE(PAIRS_W2, 2)
    GATE_STAGE(PAIRS_W3, 3)
    GATE_STAGE(PAIRS_W4, 4)

    // Wire 5: pair within one f2 -> diag/off-diag packed constants + swap
    {
        const float* g = G1 + 5*8;
        f2 vdr = f2{g[0], g[6]}, vdi = f2{g[1], g[7]};   // {g00, g11}
        f2 vor_= f2{g[2], g[4]}, voi = f2{g[3], g[5]};   // {g01, g10}
#define W5S(m) { f2 ar = sr##m, ai = si##m; \
    f2 ars = __builtin_shufflevector(ar, ar, 1, 0); \
    f2 ais = __builtin_shufflevector(ai, ai, 1, 0); \
    sr##m = vdr*ar - vdi*ai + vor_*ars - voi*ais; \
    si##m = vdr*ai + vdi*ar + vor_*ais + voi*ars; }
        REP32(W5S)
    }

    // Wires 6..11: cross-lane pairs via shfl_xor, one block per wire
#define SHF(m) { f2 s_r = sr##m, s_i = si##m; f2 o_r, o_i; \
    o_r.x = __shfl_xor(s_r.x, XM); o_r.y = __shfl_xor(s_r.y, XM); \
    o_i.x = __shfl_xor(s_i.x, XM); o_i.y = __shfl_xor(s_i.y, XM); \
    sr##m = gar*s_r - gai*s_i + gbr*o_r - gbi*o_i; \
    si##m = gar*s_i + gai*s_r + gbr*o_i + gbi*o_r; }
#define SHF_STAGE(W, SHIFT) { const float* g = G1 + (W)*8; \
    const int XM = 1 << (SHIFT); \
    const int myBit = (lane >> (SHIFT)) & 1; \
    float gar = myBit ? g[6] : g[0]; float gai = myBit ? g[7] : g[1]; \
    float gbr = myBit ? g[4] : g[2]; float gbi = myBit ? g[5] : g[3]; \
    REP32(SHF) }
    SHF_STAGE(6, 5)
    SHF_STAGE(7, 4)
    SHF_STAGE(8, 3)
    SHF_STAGE(9, 2)
    SHF_STAGE(10, 1)
    SHF_STAGE(11, 0)

    // Measurement: packed signed accumulators t_k (sign = parity(m>>k), literal fold)
    f2 t0 = f2{0.f,0.f}, t1 = f2{0.f,0.f}, t2 = f2{0.f,0.f},
       t3 = f2{0.f,0.f}, t4 = f2{0.f,0.f};
#define MEAS(m) { f2 p = sr##m*sr##m + si##m*si##m; \
    t0 += ((__builtin_popcount((unsigned)(m)     ) & 1) ? -p : p); \
    t1 += ((__builtin_popcount((unsigned)((m)>>1)) & 1) ? -p : p); \
    t2 += ((__builtin_popcount((unsigned)((m)>>2)) & 1) ? -p : p); \
    t3 += ((__builtin_popcount((unsigned)((m)>>3)) & 1) ? -p : p); \
    t4 += ((__builtin_popcount((unsigned)((m)>>4)) & 1) ? -p : p); }
    REP32(MEAS)

    float s0 = t4.x + t4.y;   // wire 0: parity(m>>4)
    float s1 = t3.x + t3.y;
    float s2 = t2.x + t2.y;
    float s3 = t1.x + t1.y;
    float s4 = t0.x + t0.y;   // wire 4: parity(m)
    float s5 = t0.x - t0.y;   // wire 5: parity(m)^half

    const float T = s5;       // full-parity signed sum, shared by wires 6..11
    float r0=s0, r1=s1, r2=s2, r3=s3, r4=s4, r5=s5;
    float r6  = (__builtin_popcount((unsigned)(lane>>5)) & 1) ? -T : T;
    float r7  = (__builtin_popcount((unsigned)(lane>>4)) & 1) ? -T : T;
    float r8  = (__builtin_popcount((unsigned)(lane>>3)) & 1) ? -T : T;
    float r9  = (__builtin_popcount((unsigned)(lane>>2)) & 1) ? -T : T;
    float r10 = (__builtin_popcount((unsigned)(lane>>1)) & 1) ? -T : T;
    float r11 = (__builtin_popcount((unsigned)(lane   )) & 1) ? -T : T;

    #pragma unroll
    for (int d = 1; d < 64; d <<= 1){
        r0  += __shfl_xor(r0,  d);
        r1  += __shfl_xor(r1,  d);
        r2  += __shfl_xor(r2,  d);
        r3  += __shfl_xor(r3,  d);
        r4  += __shfl_xor(r4,  d);
        r5  += __shfl_xor(r5,  d);
        r6  += __shfl_xor(r6,  d);
        r7  += __shfl_xor(r7,  d);
        r8  += __shfl_xor(r8,  d);
        r9  += __shfl_xor(r9,  d);
        r10 += __shfl_xor(r10, d);
        r11 += __shfl_xor(r11, d);
    }
    if (lane == 0){
        float* o = out + (size_t)b * NQ;
        o[0]=r0; o[1]=r1; o[2]=r2; o[3]=r3; o[4]=r4; o[5]=r5;
        o[6]=r6; o[7]=r7; o[8]=r8; o[9]=r9; o[10]=r10; o[11]=r11;
    }
}

extern "C" void kernel_launch(void* const* d_in, const int* in_sizes, int n_in,
                              void* d_out, int out_size, void* d_ws, size_t ws_size,
                              hipStream_t stream){
    const float* x   = (const float*)d_in[0];
    const float* wts = (const float*)d_in[1];
    float* out = (float*)d_out;
    float* gbuf = (float*)d_ws;           // 24 gates * 8 floats = 768 B
    const int B = in_sizes[0] / NQ;

    precompute_gates<<<1, 64, 0, stream>>>(wts, gbuf);
    qsim<<<(B + 3) / 4, 256, 0, stream>>>(x, gbuf, out, B);
}

// Round 6
// 40.970 us; speedup vs baseline: 23.7747x; 2.3825x over previous
//
#include <hip/hip_runtime.h>
#include <hip/hip_fp16.h>

#define NQ 12

struct C2 { float r, i; };
__device__ __forceinline__ C2 cmul(C2 a, C2 b){ return C2{a.r*b.r - a.i*b.i, a.r*b.i + a.i*b.r}; }
__device__ __forceinline__ C2 cadd(C2 a, C2 b){ return C2{a.r + b.r, a.i + b.i}; }

// Precompute the 24 fused per-wire unitaries G = RZ(c)*RY(b)*RX(a)
// (layer-major: t = layer*12 + wire), 8 floats each, at d_ws offset 0.
__global__ void precompute_gates(const float* __restrict__ wts, float* __restrict__ gout){
    int t = threadIdx.x;
    if (t >= 2*NQ) return;
    float a = wts[3*t], bb = wts[3*t+1], c = wts[3*t+2];
    float sa, ca, sb, cb, sc, cc;
    sincosf(0.5f*a,  &sa, &ca);
    sincosf(0.5f*bb, &sb, &cb);
    sincosf(0.5f*c,  &sc, &cc);
    C2 rx00{ca,0.f}, rx01{0.f,-sa}, rx10{0.f,-sa}, rx11{ca,0.f};
    C2 ry00{cb,0.f}, ry01{-sb,0.f}, ry10{sb,0.f}, ry11{cb,0.f};
    C2 m00 = cadd(cmul(ry00,rx00), cmul(ry01,rx10));
    C2 m01 = cadd(cmul(ry00,rx01), cmul(ry01,rx11));
    C2 m10 = cadd(cmul(ry10,rx00), cmul(ry11,rx10));
    C2 m11 = cadd(cmul(ry10,rx01), cmul(ry11,rx11));
    C2 e0{cc,-sc}, e1{cc,sc};
    C2 g00 = cmul(e0,m00), g01 = cmul(e0,m01);
    C2 g10 = cmul(e1,m10), g11 = cmul(e1,m11);
    float* o = gout + t*8;
    o[0]=g00.r; o[1]=g00.i; o[2]=g01.r; o[3]=g01.i;
    o[4]=g10.r; o[5]=g10.i; o[6]=g11.r; o[7]=g11.i;
}

// Build A = G1_0 x ... x G1_5 (64x64, wire w <-> bit 5-w) and
// B = G1_6 x ... x G1_11, column-major, f16 complex (half2 per entry).
// AB[0..4095] = A[j*64+r], AB[4096..8191] = B[l*64+c].
__global__ void build_AB(const float* __restrict__ gbuf, unsigned int* __restrict__ AB){
    int tid = blockIdx.x * blockDim.x + threadIdx.x;   // 0..8191
    if (tid >= 8192) return;
    int part = tid >> 12;          // 0 = A (gates 12..17), 1 = B (gates 18..23)
    int e    = tid & 4095;
    int row  = e & 63;             // r (A) or c (B)
    int col  = e >> 6;             // j (A) or l (B)
    const float* gb = gbuf + (part ? 18*8 : 12*8);
    float cr = 1.f, ci = 0.f;
    #pragma unroll
    for (int w = 0; w < 6; ++w){
        int rb = (row >> (5-w)) & 1;
        int cb = (col >> (5-w)) & 1;
        const float* g = gb + w*8 + (rb*2+cb)*2;
        float ar = g[0], ai = g[1];
        float nr = cr*ar - ci*ai, ni = cr*ai + ci*ar;
        cr = nr; ci = ni;
    }
    __half2 h = __floats2half2_rn(cr, ci);
    AB[tid] = *reinterpret_cast<unsigned int*>(&h);
}

// Rank-2 collapse: pre-layer-1 state S[j][l] = H2[j] * LP_{j&1}[l]
// (gray-folded product state; layer-0 CNOTs inside). Layer-1 = A (x) B, so
// D = A S B^T = u0 (x) w0 + u1 (x) w1 with
//   u_p = A * (H2 masked to j&1==p),  w_p = B * LP_p  (64-dim matvecs).
// Measurement signs are separable sigma(r)*tau(c), so all 12 outputs are
// prefix-parity wave reductions of |u|^2 / u0*conj(u1) (rows) and of the
// w-quantities (cols). Work/element ~0.1 MFLOP vs ~0.9 for full-state gates.
// One wave = one batch element; lane = row index r = col index c.

#define CMULSEL(acc, vw, bit) { \
    float ar_ = (bit) ? vw##r1 : vw##r0; float ai_ = (bit) ? vw##i1 : vw##i0; \
    float nr_ = acc##r*ar_ - acc##i*ai_; float ni_ = acc##r*ai_ + acc##i*ar_; \
    acc##r = nr_; acc##i = ni_; }

// prefix-parity signed reductions: P##R_w = sum_r (-1)^{parity(r>>(5-w))} v[r],
// valid at lane 0.
#define CHAIN6(v, P) \
    float P##d1 = (v) - __shfl_xor((v),32); \
    float P##d2 = P##d1 - __shfl_xor(P##d1,16); \
    float P##d3 = P##d2 - __shfl_xor(P##d2,8); \
    float P##d4 = P##d3 - __shfl_xor(P##d3,4); \
    float P##d5 = P##d4 - __shfl_xor(P##d4,2); \
    float P##R5 = P##d5 - __shfl_xor(P##d5,1); \
    float P##R0 = P##d1; P##R0 += __shfl_xor(P##R0,16); P##R0 += __shfl_xor(P##R0,8); \
        P##R0 += __shfl_xor(P##R0,4); P##R0 += __shfl_xor(P##R0,2); P##R0 += __shfl_xor(P##R0,1); \
    float P##R1 = P##d2; P##R1 += __shfl_xor(P##R1,8); P##R1 += __shfl_xor(P##R1,4); \
        P##R1 += __shfl_xor(P##R1,2); P##R1 += __shfl_xor(P##R1,1); \
    float P##R2 = P##d3; P##R2 += __shfl_xor(P##R2,4); P##R2 += __shfl_xor(P##R2,2); P##R2 += __shfl_xor(P##R2,1); \
    float P##R3 = P##d4; P##R3 += __shfl_xor(P##R3,2); P##R3 += __shfl_xor(P##R3,1); \
    float P##R4 = P##d5; P##R4 += __shfl_xor(P##R4,1);

#define PLAIN6(v, name) \
    float name = (v); name += __shfl_xor(name,32); name += __shfl_xor(name,16); \
    name += __shfl_xor(name,8); name += __shfl_xor(name,4); name += __shfl_xor(name,2); name += __shfl_xor(name,1);

__global__ __launch_bounds__(256)
void qsim(const float* __restrict__ x, const float* __restrict__ Gm,
          const unsigned int* __restrict__ AB, float* __restrict__ out, int B){
    __shared__ unsigned int lAB[8192];     // 32 KB: A then B, f16 complex, col-major
    __shared__ float2 lH2[4][64];          // per-wave H2 broadcast buffer
    __shared__ float2 lBase[4][64];        // per-wave LP-base broadcast buffer

    const int tid = threadIdx.x;
    {   // stage A,B into LDS (coalesced uint4)
        const uint4* src = reinterpret_cast<const uint4*>(AB);
        uint4* dst = reinterpret_cast<uint4*>(lAB);
        #pragma unroll
        for (int k = 0; k < 8; ++k) dst[tid + k*256] = src[tid + k*256];
    }
    __syncthreads();

    const int lane = tid & 63;
    const int wid  = tid >> 6;
    const int b    = blockIdx.x * 4 + wid;
    if (b >= B) return;
    const float* xp = x + (size_t)b * NQ;

    // v_w = G0_w * [cos(x/2), sin(x/2)]^T (wave-uniform)
#define DECLV(w) float v##w##r0, v##w##i0, v##w##r1, v##w##i1;
    DECLV(0) DECLV(1) DECLV(2) DECLV(3) DECLV(4) DECLV(5)
    DECLV(6) DECLV(7) DECLV(8) DECLV(9) DECLV(10) DECLV(11)
#define LOADV(w) { float sx, cx; __sincosf(0.5f * xp[w], &sx, &cx); \
    const float* g = Gm + (w)*8; \
    v##w##r0 = g[0]*cx + g[2]*sx;  v##w##i0 = g[1]*cx + g[3]*sx; \
    v##w##r1 = g[4]*cx + g[6]*sx;  v##w##i1 = g[5]*cx + g[7]*sx; }
    LOADV(0) LOADV(1) LOADV(2) LOADV(3) LOADV(4) LOADV(5)
    LOADV(6) LOADV(7) LOADV(8) LOADV(9) LOADV(10) LOADV(11)

    // H2[j] for j = lane: gray product over wires 0..5 (wire0 <-> bit5)
    {
        const int g0 = (lane>>5)&1;
        const int g1 = ((lane>>4)^(lane>>5))&1;
        const int g2 = ((lane>>3)^(lane>>4))&1;
        const int g3 = ((lane>>2)^(lane>>3))&1;
        const int g4 = ((lane>>1)^(lane>>2))&1;
        const int g5 = ( lane    ^(lane>>1))&1;
        float h2r = g0 ? v0r1 : v0r0, h2i = g0 ? v0i1 : v0i0;
        CMULSEL(h2, v1, g1) CMULSEL(h2, v2, g2) CMULSEL(h2, v3, g3)
        CMULSEL(h2, v4, g4) CMULSEL(h2, v5, g5)
        lH2[wid][lane] = float2{h2r, h2i};
    }
    // LP base over wires 7..11 for l = lane (wire 6 handled via P0/P1 split)
    {
        const int b1 = ((lane>>4)^(lane>>5))&1;   // wire 7
        const int b2 = ((lane>>3)^(lane>>4))&1;   // wire 8
        const int b3 = ((lane>>2)^(lane>>3))&1;   // wire 9
        const int b4 = ((lane>>1)^(lane>>2))&1;   // wire 10
        const int b5 = ( lane    ^(lane>>1))&1;   // wire 11
        float bsr = b1 ? v7r1 : v7r0, bsi = b1 ? v7i1 : v7i0;
        CMULSEL(bs, v8, b2) CMULSEL(bs, v9, b3) CMULSEL(bs, v10, b4) CMULSEL(bs, v11, b5)
        lBase[wid][lane] = float2{bsr, bsi};
    }
    // (same-wave LDS write->read; compiler inserts lgkmcnt)

    // u_p[r] = sum_{j: j&1==p} A[r][j] * H2[j]   (outer-product accumulation,
    // A column reads conflict-free: addr = j*256 + lane*4)
    float u0r=0.f,u0i=0.f,u1r=0.f,u1i=0.f;
    #pragma unroll
    for (int j = 0; j < 64; j += 2){
        {
            float2 h = lH2[wid][j];
            unsigned int av = lAB[j*64 + lane];
            float2 a = __half22float2(*reinterpret_cast<const __half2*>(&av));
            u0r += a.x*h.x - a.y*h.y;  u0i += a.x*h.y + a.y*h.x;
        }
        {
            float2 h = lH2[wid][j+1];
            unsigned int av = lAB[(j+1)*64 + lane];
            float2 a = __half22float2(*reinterpret_cast<const __half2*>(&av));
            u1r += a.x*h.x - a.y*h.y;  u1i += a.x*h.y + a.y*h.x;
        }
    }

    // P_h[c] = sum_{l: l5==h} B[c][l]*base[l];  w_p = v6[p]*P0 + v6[1-p]*P1
    float P0r=0.f,P0i=0.f,P1r=0.f,P1i=0.f;
    #pragma unroll
    for (int l = 0; l < 32; ++l){
        float2 t = lBase[wid][l];
        unsigned int bv = lAB[4096 + l*64 + lane];
        float2 bb = __half22float2(*reinterpret_cast<const __half2*>(&bv));
        P0r += bb.x*t.x - bb.y*t.y;  P0i += bb.x*t.y + bb.y*t.x;
    }
    #pragma unroll
    for (int l = 32; l < 64; ++l){
        float2 t = lBase[wid][l];
        unsigned int bv = lAB[4096 + l*64 + lane];
        float2 bb = __half22float2(*reinterpret_cast<const __half2*>(&bv));
        P1r += bb.x*t.x - bb.y*t.y;  P1i += bb.x*t.y + bb.y*t.x;
    }
    float w0r = (v6r0*P0r - v6i0*P0i) + (v6r1*P1r - v6i1*P1i);
    float w0i = (v6r0*P0i + v6i0*P0r) + (v6r1*P1i + v6i1*P1r);
    float w1r = (v6r1*P0r - v6i1*P0i) + (v6r0*P1r - v6i0*P1i);
    float w1i = (v6r1*P0i + v6i1*P0r) + (v6r0*P1i + v6i0*P1r);

    // Row quadratics (lane = r):  a0, a1, z = u0*conj(u1)
    float a0 = u0r*u0r + u0i*u0i;
    float a1 = u1r*u1r + u1i*u1i;
    float zr = u0r*u1r + u0i*u1i;
    float zi = u0i*u1r - u0r*u1i;
    // Col quadratics (lane = c):  b0, b1, y = w0*conj(w1)
    float b0 = w0r*w0r + w0i*w0i;
    float b1 = w1r*w1r + w1i*w1i;
    float yr = w0r*w1r + w0i*w1i;
    float yi = w0i*w1r - w0r*w1i;

    // Row signed reductions (sigma_w = parity(r >> (5-w)))
    CHAIN6(a0, Ra0_) CHAIN6(a1, Ra1_) CHAIN6(zr, Rzr_) CHAIN6(zi, Rzi_)
    // Col signed reductions (tau_m = parity(c >> (5-m))) + plain sums
    CHAIN6(b0, Cb0_) CHAIN6(b1, Cb1_) CHAIN6(yr, Cyr_) CHAIN6(yi, Cyi_)
    PLAIN6(b0, Pb0) PLAIN6(b1, Pb1) PLAIN6(yr, Pyr) PLAIN6(yi, Pyi)

    if (lane == 0){
        float* o = out + (size_t)b * NQ;
        // wires 0..5: out = R_w(a0)*Cp(b0) + R_w(a1)*Cp(b1) + 2[R_w(zr)Cp(yr) - R_w(zi)Cp(yi)]
#define OUTW(w) o[w] = Ra0_R##w*Pb0 + Ra1_R##w*Pb1 + 2.f*(Rzr_R##w*Pyr - Rzi_R##w*Pyi);
        OUTW(0) OUTW(1) OUTW(2) OUTW(3) OUTW(4) OUTW(5)
        // wires 6..11 (m=w-6): sigma = parity(r) (= R5), tau = C_m
#define OUTM(m) o[6+(m)] = Ra0_R5*Cb0_R##m + Ra1_R5*Cb1_R##m + 2.f*(Rzr_R5*Cyr_R##m - Rzi_R5*Cyi_R##m);
        OUTM(0) OUTM(1) OUTM(2) OUTM(3) OUTM(4) OUTM(5)
    }
}

extern "C" void kernel_launch(void* const* d_in, const int* in_sizes, int n_in,
                              void* d_out, int out_size, void* d_ws, size_t ws_size,
                              hipStream_t stream){
    const float* x   = (const float*)d_in[0];
    const float* wts = (const float*)d_in[1];
    float* out = (float*)d_out;
    float* gbuf = (float*)d_ws;                                        // 768 B
    unsigned int* AB = (unsigned int*)((char*)d_ws + 1024);            // 32 KB (A then B, f16)
    const int B = in_sizes[0] / NQ;

    precompute_gates<<<1, 64, 0, stream>>>(wts, gbuf);
    build_AB<<<32, 256, 0, stream>>>(gbuf, AB);
    qsim<<<(B + 3) / 4, 256, 0, stream>>>(x, gbuf, AB, out, B);
}

// Round 8
// 35.207 us; speedup vs baseline: 27.6663x; 1.1637x over previous
//
#include <hip/hip_runtime.h>

#define NQ 12

typedef _Float16 hf2 __attribute__((ext_vector_type(2)));

#if defined(__has_builtin)
#if __has_builtin(__builtin_amdgcn_fdot2)
#define FDOT2(a,b,c) __builtin_amdgcn_fdot2((a),(b),(c),false)
#endif
#endif
#ifndef FDOT2
__device__ __forceinline__ float fdot2_sw(hf2 a, hf2 b, float c){
    return c + (float)a.x*(float)b.x + (float)a.y*(float)b.y;
}
#define FDOT2(a,b,c) fdot2_sw((a),(b),(c))
#endif

struct C2 { float r, i; };
__device__ __forceinline__ C2 cmul(C2 a, C2 b){ return C2{a.r*b.r - a.i*b.i, a.r*b.i + a.i*b.r}; }
__device__ __forceinline__ C2 cadd(C2 a, C2 b){ return C2{a.r + b.r, a.i + b.i}; }

struct __align__(8) U2 { unsigned x, y; };
struct V4 { float r0, i0, r1, i1; };

__device__ __forceinline__ unsigned pack2(float a, float b){
    union { hf2 h; unsigned u; } cv;
    cv.h.x = (_Float16)a; cv.h.y = (_Float16)b;
    return cv.u;
}
__device__ __forceinline__ hf2 unpack2(unsigned u){
    union { unsigned u; hf2 h; } cv; cv.u = u; return cv.h;
}

// Fused per-wire unitary G = RZ(c)*RY(b)*RX(a) for weight-triple t -> 8 floats.
__device__ __forceinline__ void fused_gate(const float* __restrict__ wts, int t, float* o){
    float a = wts[3*t], bb = wts[3*t+1], c = wts[3*t+2];
    float sa, ca, sb, cb, sc, cc;
    sincosf(0.5f*a,  &sa, &ca);
    sincosf(0.5f*bb, &sb, &cb);
    sincosf(0.5f*c,  &sc, &cc);
    C2 rx00{ca,0.f}, rx01{0.f,-sa}, rx10{0.f,-sa}, rx11{ca,0.f};
    C2 ry00{cb,0.f}, ry01{-sb,0.f}, ry10{sb,0.f}, ry11{cb,0.f};
    C2 m00 = cadd(cmul(ry00,rx00), cmul(ry01,rx10));
    C2 m01 = cadd(cmul(ry00,rx01), cmul(ry01,rx11));
    C2 m10 = cadd(cmul(ry10,rx00), cmul(ry11,rx10));
    C2 m11 = cadd(cmul(ry10,rx01), cmul(ry11,rx11));
    C2 e0{cc,-sc}, e1{cc,sc};
    C2 g00 = cmul(e0,m00), g01 = cmul(e0,m01);
    C2 g10 = cmul(e1,m10), g11 = cmul(e1,m11);
    o[0]=g00.r; o[1]=g00.i; o[2]=g01.r; o[3]=g01.i;
    o[4]=g10.r; o[5]=g10.i; o[6]=g11.r; o[7]=g11.i;
}

// v_w = G0_w * [cos(x/2), sin(x/2)]^T
__device__ __forceinline__ V4 loadv(const float* __restrict__ lG, int w, float xw){
    float sx, cx;
    __sincosf(0.5f * xw, &sx, &cx);
    const float* g = lG + w*8;
    V4 v;
    v.r0 = g[0]*cx + g[2]*sx;  v.i0 = g[1]*cx + g[3]*sx;
    v.r1 = g[4]*cx + g[6]*sx;  v.i1 = g[5]*cx + g[7]*sx;
    return v;
}

__device__ __forceinline__ void cmulsel(float& ar, float& ai, const V4& v, int bit){
    float br = bit ? v.r1 : v.r0;
    float bi = bit ? v.i1 : v.i0;
    float nr = ar*br - ai*bi, ni = ar*bi + ai*br;
    ar = nr; ai = ni;
}

// Build A = (x) G1_{0..5}, B = (x) G1_{6..11} (64x64, f16 complex), with
// PAIR-INTERLEAVED layout: entry (row, col) at part*4096 + (col>>1)*128
// + row*2 + (col&1), so a lane's (col, col+1) pair is one 8-byte read.
__global__ void build_AB(const float* __restrict__ wts, unsigned* __restrict__ AB){
    __shared__ float sG[192];
    const int tid = threadIdx.x;
    if (tid < 24) fused_gate(wts, tid, sG + tid*8);
    __syncthreads();
    const int idx  = blockIdx.x * 256 + tid;    // 0..8191
    const int part = idx >> 12;                 // 0 = A (gates 12..17), 1 = B
    const int e    = idx & 4095;
    const int row  = e & 63;
    const int col  = e >> 6;
    const float* gb = sG + (part ? 18*8 : 12*8);
    float cr = 1.f, ci = 0.f;
    #pragma unroll
    for (int w = 0; w < 6; ++w){
        int rb = (row >> (5-w)) & 1;
        int cb = (col >> (5-w)) & 1;
        const float* g = gb + w*8 + (rb*2+cb)*2;
        float ar = g[0], ai = g[1];
        float nr = cr*ar - ci*ai, ni = cr*ai + ci*ar;
        cr = nr; ci = ni;
    }
    AB[part*4096 + (col>>1)*128 + row*2 + (col&1)] = pack2(cr, ci);
}

// prefix-parity signed reductions: P##R_w = sum_r (-1)^{parity(r>>(5-w))} v[r], valid at lane 0.
#define CHAIN6(v, P) \
    float P##d1 = (v) - __shfl_xor((v),32); \
    float P##d2 = P##d1 - __shfl_xor(P##d1,16); \
    float P##d3 = P##d2 - __shfl_xor(P##d2,8); \
    float P##d4 = P##d3 - __shfl_xor(P##d3,4); \
    float P##d5 = P##d4 - __shfl_xor(P##d4,2); \
    float P##R5 = P##d5 - __shfl_xor(P##d5,1); \
    float P##R0 = P##d1; P##R0 += __shfl_xor(P##R0,16); P##R0 += __shfl_xor(P##R0,8); \
        P##R0 += __shfl_xor(P##R0,4); P##R0 += __shfl_xor(P##R0,2); P##R0 += __shfl_xor(P##R0,1); \
    float P##R1 = P##d2; P##R1 += __shfl_xor(P##R1,8); P##R1 += __shfl_xor(P##R1,4); \
        P##R1 += __shfl_xor(P##R1,2); P##R1 += __shfl_xor(P##R1,1); \
    float P##R2 = P##d3; P##R2 += __shfl_xor(P##R2,4); P##R2 += __shfl_xor(P##R2,2); P##R2 += __shfl_xor(P##R2,1); \
    float P##R3 = P##d4; P##R3 += __shfl_xor(P##R3,2); P##R3 += __shfl_xor(P##R3,1); \
    float P##R4 = P##d5; P##R4 += __shfl_xor(P##R4,1);

#define PLAIN6(v, name) \
    float name = (v); name += __shfl_xor(name,32); name += __shfl_xor(name,16); \
    name += __shfl_xor(name,8); name += __shfl_xor(name,4); name += __shfl_xor(name,2); name += __shfl_xor(name,1);

// Rank-2 evaluation (one wave = one batch element):
// S[j][l] = H2[j]*LP_{j&1}[l]; layer-1 = A (x) B, so
// D = u0 (x) w0 + u1 (x) w1, u_p = A*(H2 masked to j&1==p), w_p from the
// wire-6 split of B*base. 12 outputs = separable prefix-parity reductions.
__global__ __launch_bounds__(512)
void qsim(const float* __restrict__ x, const float* __restrict__ wts,
          const unsigned* __restrict__ AB, float* __restrict__ out, int B){
    __shared__ float lG[96];                      // layer-0 gates
    __shared__ __align__(16) unsigned lAB[8192];  // 32 KB A,B f16 pairs
    __shared__ U2 lH[8][64];                      // 4 KB per-wave broadcast

    const int tid = threadIdx.x;
    {   // stage A,B (L2-resident after first blocks)
        const uint4* src = reinterpret_cast<const uint4*>(AB);
        uint4* dst = reinterpret_cast<uint4*>(lAB);
        #pragma unroll
        for (int k = 0; k < 4; ++k) dst[tid + k*512] = src[tid + k*512];
    }
    if (tid < 12) fused_gate(wts, tid, lG + tid*8);
    __syncthreads();

    const int lane = tid & 63;
    const int wid  = tid >> 6;
    const int b    = blockIdx.x * 8 + wid;
    if (b >= B) return;
    const float* xp = x + (size_t)b * NQ;

    V4 v0  = loadv(lG, 0,  xp[0]);
    V4 v1  = loadv(lG, 1,  xp[1]);
    V4 v2  = loadv(lG, 2,  xp[2]);
    V4 v3  = loadv(lG, 3,  xp[3]);
    V4 v4  = loadv(lG, 4,  xp[4]);
    V4 v5  = loadv(lG, 5,  xp[5]);
    V4 v6  = loadv(lG, 6,  xp[6]);
    V4 v7  = loadv(lG, 7,  xp[7]);
    V4 v8  = loadv(lG, 8,  xp[8]);
    V4 v9  = loadv(lG, 9,  xp[9]);
    V4 v10 = loadv(lG, 10, xp[10]);
    V4 v11 = loadv(lG, 11, xp[11]);

    // H2[j], j = lane: gray product over wires 0..5 (wire0 <-> bit5)
    {
        const int g0 = (lane>>5)&1;
        const int g1 = ((lane>>4)^(lane>>5))&1;
        const int g2 = ((lane>>3)^(lane>>4))&1;
        const int g3 = ((lane>>2)^(lane>>3))&1;
        const int g4 = ((lane>>1)^(lane>>2))&1;
        const int g5 = ( lane    ^(lane>>1))&1;
        float hr_ = g0 ? v0.r1 : v0.r0;
        float hi_ = g0 ? v0.i1 : v0.i0;
        cmulsel(hr_, hi_, v1, g1);
        cmulsel(hr_, hi_, v2, g2);
        cmulsel(hr_, hi_, v3, g3);
        cmulsel(hr_, hi_, v4, g4);
        cmulsel(hr_, hi_, v5, g5);
        U2 t; t.x = pack2(hr_, -hi_); t.y = pack2(hi_, hr_);
        lH[wid][lane] = t;
    }

    // u_p[r] = sum_{j: j&1==p} A[r][j]*H2[j]; one b64 A read per j-pair,
    // 2 fdot2 per complex MAC with pre-packed (h.r,-h.i)/(h.i,h.r).
    float u0r=0.f,u0i=0.f,u1r=0.f,u1i=0.f;
    #pragma unroll
    for (int p = 0; p < 32; ++p){
        U2 av = *reinterpret_cast<const U2*>(&lAB[p*128 + lane*2]);
        U2 q0 = lH[wid][2*p];
        U2 q1 = lH[wid][2*p+1];
        hf2 a0 = unpack2(av.x), a1 = unpack2(av.y);
        u0r = FDOT2(a0, unpack2(q0.x), u0r);
        u0i = FDOT2(a0, unpack2(q0.y), u0i);
        u1r = FDOT2(a1, unpack2(q1.x), u1r);
        u1i = FDOT2(a1, unpack2(q1.y), u1i);
    }

    // base over wires 7..11 -> overwrite lH (same-wave DS order: safe)
    {
        const int b1 = ((lane>>4)^(lane>>5))&1;   // wire 7
        const int b2 = ((lane>>3)^(lane>>4))&1;   // wire 8
        const int b3 = ((lane>>2)^(lane>>3))&1;   // wire 9
        const int b4 = ((lane>>1)^(lane>>2))&1;   // wire 10
        const int b5 = ( lane    ^(lane>>1))&1;   // wire 11
        float br_ = b1 ? v7.r1 : v7.r0;
        float bi_ = b1 ? v7.i1 : v7.i0;
        cmulsel(br_, bi_, v8,  b2);
        cmulsel(br_, bi_, v9,  b3);
        cmulsel(br_, bi_, v10, b4);
        cmulsel(br_, bi_, v11, b5);
        U2 t; t.x = pack2(br_, -bi_); t.y = pack2(bi_, br_);
        lH[wid][lane] = t;
    }

    // P_h[c] = sum_{l: bit5(l)==h} B[c][l]*base[l]
    float P0r=0.f,P0i=0.f,P1r=0.f,P1i=0.f;
    #pragma unroll
    for (int p = 0; p < 16; ++p){
        U2 bv = *reinterpret_cast<const U2*>(&lAB[4096 + p*128 + lane*2]);
        U2 q0 = lH[wid][2*p];
        U2 q1 = lH[wid][2*p+1];
        hf2 e0 = unpack2(bv.x), e1 = unpack2(bv.y);
        P0r = FDOT2(e0, unpack2(q0.x), P0r);
        P0i = FDOT2(e0, unpack2(q0.y), P0i);
        P0r = FDOT2(e1, unpack2(q1.x), P0r);
        P0i = FDOT2(e1, unpack2(q1.y), P0i);
    }
    #pragma unroll
    for (int p = 16; p < 32; ++p){
        U2 bv = *reinterpret_cast<const U2*>(&lAB[4096 + p*128 + lane*2]);
        U2 q0 = lH[wid][2*p];
        U2 q1 = lH[wid][2*p+1];
        hf2 e0 = unpack2(bv.x), e1 = unpack2(bv.y);
        P1r = FDOT2(e0, unpack2(q0.x), P1r);
        P1i = FDOT2(e0, unpack2(q0.y), P1i);
        P1r = FDOT2(e1, unpack2(q1.x), P1r);
        P1i = FDOT2(e1, unpack2(q1.y), P1i);
    }
    float w0r = (v6.r0*P0r - v6.i0*P0i) + (v6.r1*P1r - v6.i1*P1i);
    float w0i = (v6.r0*P0i + v6.i0*P0r) + (v6.r1*P1i + v6.i1*P1r);
    float w1r = (v6.r1*P0r - v6.i1*P0i) + (v6.r0*P1r - v6.i0*P1i);
    float w1i = (v6.r1*P0i + v6.i1*P0r) + (v6.r0*P1i + v6.i0*P1r);

    // Row quadratics (lane = r) and col quadratics (lane = c)
    float a0 = u0r*u0r + u0i*u0i;
    float a1 = u1r*u1r + u1i*u1i;
    float zr = u0r*u1r + u0i*u1i;
    float zi = u0i*u1r - u0r*u1i;
    float b0 = w0r*w0r + w0i*w0i;
    float b1 = w1r*w1r + w1i*w1i;
    float yr = w0r*w1r + w0i*w1i;
    float yi = w0i*w1r - w0r*w1i;

    CHAIN6(a0, Ra0_) CHAIN6(a1, Ra1_) CHAIN6(zr, Rzr_) CHAIN6(zi, Rzi_)
    CHAIN6(b0, Cb0_) CHAIN6(b1, Cb1_) CHAIN6(yr, Cyr_) CHAIN6(yi, Cyi_)
    PLAIN6(b0, Pb0) PLAIN6(b1, Pb1) PLAIN6(yr, Pyr) PLAIN6(yi, Pyi)

    if (lane == 0){
        float* o = out + (size_t)b * NQ;
#define OUTW(w) o[w] = Ra0_R##w*Pb0 + Ra1_R##w*Pb1 + 2.f*(Rzr_R##w*Pyr - Rzi_R##w*Pyi);
        OUTW(0) OUTW(1) OUTW(2) OUTW(3) OUTW(4) OUTW(5)
#define OUTM(m) o[6+(m)] = Ra0_R5*Cb0_R##m + Ra1_R5*Cb1_R##m + 2.f*(Rzr_R5*Cyr_R##m - Rzi_R5*Cyi_R##m);
        OUTM(0) OUTM(1) OUTM(2) OUTM(3) OUTM(4) OUTM(5)
    }
}

extern "C" void kernel_launch(void* const* d_in, const int* in_sizes, int n_in,
                              void* d_out, int out_size, void* d_ws, size_t ws_size,
                              hipStream_t stream){
    const float* x   = (const float*)d_in[0];
    const float* wts = (const float*)d_in[1];
    float* out = (float*)d_out;
    unsigned* AB = (unsigned*)d_ws;     // 32 KB f16 A/B matrices
    const int B = in_sizes[0] / NQ;

    build_AB<<<32, 256, 0, stream>>>(wts, AB);
    qsim<<<(B + 7) / 8, 512, 0, stream>>>(x, wts, AB, out, B);
}

// Round 9
// 27.941 us; speedup vs baseline: 34.8617x; 1.2601x over previous
//
#include <hip/hip_runtime.h>

#define NQ 12

typedef _Float16 hf2 __attribute__((ext_vector_type(2)));

#if defined(__has_builtin)
#if __has_builtin(__builtin_amdgcn_fdot2)
#define FDOT2(a,b,c) __builtin_amdgcn_fdot2((a),(b),(c),false)
#endif
#endif
#ifndef FDOT2
__device__ __forceinline__ float fdot2_sw(hf2 a, hf2 b, float c){
    return c + (float)a.x*(float)b.x + (float)a.y*(float)b.y;
}
#define FDOT2(a,b,c) fdot2_sw((a),(b),(c))
#endif

struct C2 { float r, i; };
__device__ __forceinline__ C2 cmul(C2 a, C2 b){ return C2{a.r*b.r - a.i*b.i, a.r*b.i + a.i*b.r}; }
__device__ __forceinline__ C2 cadd(C2 a, C2 b){ return C2{a.r + b.r, a.i + b.i}; }

struct __align__(8) U2 { unsigned x, y; };
struct V4 { float r0, i0, r1, i1; };

__device__ __forceinline__ unsigned pack2(float a, float b){
    union { hf2 h; unsigned u; } cv;
    cv.h.x = (_Float16)a; cv.h.y = (_Float16)b;
    return cv.u;
}
__device__ __forceinline__ hf2 unpack2(unsigned u){
    union { unsigned u; hf2 h; } cv; cv.u = u; return cv.h;
}

// Fused per-wire unitary G = RZ(c)*RY(b)*RX(a) for weight-triple t -> 8 floats.
__device__ __forceinline__ void fused_gate(const float* __restrict__ wts, int t, float* o){
    float a = wts[3*t], bb = wts[3*t+1], c = wts[3*t+2];
    float sa, ca, sb, cb, sc, cc;
    sincosf(0.5f*a,  &sa, &ca);
    sincosf(0.5f*bb, &sb, &cb);
    sincosf(0.5f*c,  &sc, &cc);
    C2 rx00{ca,0.f}, rx01{0.f,-sa}, rx10{0.f,-sa}, rx11{ca,0.f};
    C2 ry00{cb,0.f}, ry01{-sb,0.f}, ry10{sb,0.f}, ry11{cb,0.f};
    C2 m00 = cadd(cmul(ry00,rx00), cmul(ry01,rx10));
    C2 m01 = cadd(cmul(ry00,rx01), cmul(ry01,rx11));
    C2 m10 = cadd(cmul(ry10,rx00), cmul(ry11,rx10));
    C2 m11 = cadd(cmul(ry10,rx01), cmul(ry11,rx11));
    C2 e0{cc,-sc}, e1{cc,sc};
    C2 g00 = cmul(e0,m00), g01 = cmul(e0,m01);
    C2 g10 = cmul(e1,m10), g11 = cmul(e1,m11);
    o[0]=g00.r; o[1]=g00.i; o[2]=g01.r; o[3]=g01.i;
    o[4]=g10.r; o[5]=g10.i; o[6]=g11.r; o[7]=g11.i;
}

// v_w = G0_w * [cos(x/2), sin(x/2)]^T
__device__ __forceinline__ V4 loadv(const float* __restrict__ lG, int w, float xw){
    float sx, cx;
    __sincosf(0.5f * xw, &sx, &cx);
    const float* g = lG + w*8;
    V4 v;
    v.r0 = g[0]*cx + g[2]*sx;  v.i0 = g[1]*cx + g[3]*sx;
    v.r1 = g[4]*cx + g[6]*sx;  v.i1 = g[5]*cx + g[7]*sx;
    return v;
}

__device__ __forceinline__ void cmulsel(float& ar, float& ai, const V4& v, int bit){
    float br = bit ? v.r1 : v.r0;
    float bi = bit ? v.i1 : v.i0;
    float nr = ar*br - ai*bi, ni = ar*bi + ai*br;
    ar = nr; ai = ni;
}

// Build A = (x) G1_{0..5}, B = (x) G1_{6..11} (64x64, f16 complex), with
// 4-COLUMN-GROUP layout: entry (row, col) at
//   part*4096 + (col>>2)*256 + row*4 + (col&3)
// so a lane's 4 consecutive columns for its row are one 16-byte read.
__global__ void build_AB(const float* __restrict__ wts, unsigned* __restrict__ AB){
    __shared__ float sG[192];
    const int tid = threadIdx.x;
    if (tid < 24) fused_gate(wts, tid, sG + tid*8);
    __syncthreads();
    const int idx  = blockIdx.x * 256 + tid;    // 0..8191
    const int part = idx >> 12;                 // 0 = A (gates 12..17), 1 = B
    const int e    = idx & 4095;
    const int row  = e & 63;
    const int col  = e >> 6;
    const float* gb = sG + (part ? 18*8 : 12*8);
    float cr = 1.f, ci = 0.f;
    #pragma unroll
    for (int w = 0; w < 6; ++w){
        int rb = (row >> (5-w)) & 1;
        int cb = (col >> (5-w)) & 1;
        const float* g = gb + w*8 + (rb*2+cb)*2;
        float ar = g[0], ai = g[1];
        float nr = cr*ar - ci*ai, ni = cr*ai + ci*ar;
        cr = nr; ci = ni;
    }
    AB[part*4096 + (col>>2)*256 + row*4 + (col&3)] = pack2(cr, ci);
}

// CHAIN6: prefix-parity signed reductions, P##R_w = sum_r (-1)^{parity(r>>(5-w))} v[r],
// valid at lane 0.
#define CHAIN6(v, P) \
    float P##d1 = (v) - __shfl_xor((v),32); \
    float P##d2 = P##d1 - __shfl_xor(P##d1,16); \
    float P##d3 = P##d2 - __shfl_xor(P##d2,8); \
    float P##d4 = P##d3 - __shfl_xor(P##d3,4); \
    float P##d5 = P##d4 - __shfl_xor(P##d4,2); \
    float P##R5 = P##d5 - __shfl_xor(P##d5,1); \
    float P##R0 = P##d1; P##R0 += __shfl_xor(P##R0,16); P##R0 += __shfl_xor(P##R0,8); \
        P##R0 += __shfl_xor(P##R0,4); P##R0 += __shfl_xor(P##R0,2); P##R0 += __shfl_xor(P##R0,1); \
    float P##R1 = P##d2; P##R1 += __shfl_xor(P##R1,8); P##R1 += __shfl_xor(P##R1,4); \
        P##R1 += __shfl_xor(P##R1,2); P##R1 += __shfl_xor(P##R1,1); \
    float P##R2 = P##d3; P##R2 += __shfl_xor(P##R2,4); P##R2 += __shfl_xor(P##R2,2); P##R2 += __shfl_xor(P##R2,1); \
    float P##R3 = P##d4; P##R3 += __shfl_xor(P##R3,2); P##R3 += __shfl_xor(P##R3,1); \
    float P##R4 = P##d5; P##R4 += __shfl_xor(P##R4,1);

// PLAIN6: full sum, uniform across lanes.
#define PLAIN6(v, name) \
    float name = (v); name += __shfl_xor(name,32); name += __shfl_xor(name,16); \
    name += __shfl_xor(name,8); name += __shfl_xor(name,4); name += __shfl_xor(name,2); name += __shfl_xor(name,1);

// SBFLY: signed all-reduce butterfly; lane l ends with
// (-1)^{popcount(l)} * sum_r (-1)^{popcount(r)} v_r  (multiply by sgn to uniformize).
#define SBFLY(v, name) \
    float name = (v) - __shfl_xor((v),32); \
    name = name - __shfl_xor(name,16); \
    name = name - __shfl_xor(name,8); \
    name = name - __shfl_xor(name,4); \
    name = name - __shfl_xor(name,2); \
    name = name - __shfl_xor(name,1);

// Rank-2 evaluation (one wave = one batch element):
// S[j][l] = H2[j]*LP_{j&1}[l]; layer-1 = A (x) B, so
// D = u0 (x) w0 + u1 (x) w1, u_p = A*(H2 masked to j&1==p), w_p from the
// wire-6 split of B*base. 12 outputs = separable prefix-parity reductions:
//   o[w]   = CHAIN6(alpha).Rw,  alpha_r = a0*Pb0 + a1*Pb1 + 2(zr*Pyr - zi*Pyi)
//   o[6+m] = CHAIN6(beta).Rm,   beta_c  = SA0*b0 + SA1*b1 + 2(SZr*yr - SZi*yi)
// where P* are plain col-sums and S* are full-parity row-sums (SBFLY).
__global__ __launch_bounds__(512)
void qsim(const float* __restrict__ x, const float* __restrict__ wts,
          const unsigned* __restrict__ AB, float* __restrict__ out, int B){
    __shared__ float lG[96];                       // layer-0 gates
    __shared__ __align__(16) unsigned lAB[8192];   // 32 KB A,B f16 pairs
    __shared__ __align__(16) U2 lH[8][64];         // 4 KB per-wave broadcast

    const int tid = threadIdx.x;
    {   // stage A,B (L2-resident after first blocks)
        const uint4* src = reinterpret_cast<const uint4*>(AB);
        uint4* dst = reinterpret_cast<uint4*>(lAB);
        #pragma unroll
        for (int k = 0; k < 4; ++k) dst[tid + k*512] = src[tid + k*512];
    }
    if (tid < 12) fused_gate(wts, tid, lG + tid*8);
    __syncthreads();

    const int lane = tid & 63;
    const int wid  = tid >> 6;
    const int b    = blockIdx.x * 8 + wid;
    if (b >= B) return;
    const float* xp = x + (size_t)b * NQ;

    V4 v0  = loadv(lG, 0,  xp[0]);
    V4 v1  = loadv(lG, 1,  xp[1]);
    V4 v2  = loadv(lG, 2,  xp[2]);
    V4 v3  = loadv(lG, 3,  xp[3]);
    V4 v4  = loadv(lG, 4,  xp[4]);
    V4 v5  = loadv(lG, 5,  xp[5]);
    V4 v6  = loadv(lG, 6,  xp[6]);
    V4 v7  = loadv(lG, 7,  xp[7]);
    V4 v8  = loadv(lG, 8,  xp[8]);
    V4 v9  = loadv(lG, 9,  xp[9]);
    V4 v10 = loadv(lG, 10, xp[10]);
    V4 v11 = loadv(lG, 11, xp[11]);

    // H2[j], j = lane: gray product over wires 0..5 (wire0 <-> bit5)
    {
        const int g0 = (lane>>5)&1;
        const int g1 = ((lane>>4)^(lane>>5))&1;
        const int g2 = ((lane>>3)^(lane>>4))&1;
        const int g3 = ((lane>>2)^(lane>>3))&1;
        const int g4 = ((lane>>1)^(lane>>2))&1;
        const int g5 = ( lane    ^(lane>>1))&1;
        float hr_ = g0 ? v0.r1 : v0.r0;
        float hi_ = g0 ? v0.i1 : v0.i0;
        cmulsel(hr_, hi_, v1, g1);
        cmulsel(hr_, hi_, v2, g2);
        cmulsel(hr_, hi_, v3, g3);
        cmulsel(hr_, hi_, v4, g4);
        cmulsel(hr_, hi_, v5, g5);
        U2 t; t.x = pack2(hr_, -hi_); t.y = pack2(hi_, hr_);
        lH[wid][lane] = t;
    }

    // u_p[r] = sum_{j: j&1==p} A[r][j]*H2[j]; per 4 columns: 1 A b128 + 2 H b128.
    float u0r=0.f,u0i=0.f,u1r=0.f,u1i=0.f;
    #pragma unroll
    for (int q = 0; q < 16; ++q){
        uint4 av  = *reinterpret_cast<const uint4*>(&lAB[q*256 + lane*4]);
        uint4 h01 = *reinterpret_cast<const uint4*>(&lH[wid][4*q]);
        uint4 h23 = *reinterpret_cast<const uint4*>(&lH[wid][4*q+2]);
        hf2 a0v = unpack2(av.x), a1v = unpack2(av.y);
        hf2 a2v = unpack2(av.z), a3v = unpack2(av.w);
        u0r = FDOT2(a0v, unpack2(h01.x), u0r);
        u0i = FDOT2(a0v, unpack2(h01.y), u0i);
        u1r = FDOT2(a1v, unpack2(h01.z), u1r);
        u1i = FDOT2(a1v, unpack2(h01.w), u1i);
        u0r = FDOT2(a2v, unpack2(h23.x), u0r);
        u0i = FDOT2(a2v, unpack2(h23.y), u0i);
        u1r = FDOT2(a3v, unpack2(h23.z), u1r);
        u1i = FDOT2(a3v, unpack2(h23.w), u1i);
    }

    // base over wires 7..11 -> overwrite lH (same-wave DS order: safe)
    {
        const int b1 = ((lane>>4)^(lane>>5))&1;   // wire 7
        const int b2 = ((lane>>3)^(lane>>4))&1;   // wire 8
        const int b3 = ((lane>>2)^(lane>>3))&1;   // wire 9
        const int b4 = ((lane>>1)^(lane>>2))&1;   // wire 10
        const int b5 = ( lane    ^(lane>>1))&1;   // wire 11
        float br_ = b1 ? v7.r1 : v7.r0;
        float bi_ = b1 ? v7.i1 : v7.i0;
        cmulsel(br_, bi_, v8,  b2);
        cmulsel(br_, bi_, v9,  b3);
        cmulsel(br_, bi_, v10, b4);
        cmulsel(br_, bi_, v11, b5);
        U2 t; t.x = pack2(br_, -bi_); t.y = pack2(bi_, br_);
        lH[wid][lane] = t;
    }

    // P_h[c] = sum_{l: bit5(l)==h} B[c][l]*base[l]; cols 4q..4q+3, q<8 -> P0.
    float P0r=0.f,P0i=0.f,P1r=0.f,P1i=0.f;
    #pragma unroll
    for (int q = 0; q < 8; ++q){
        uint4 bv  = *reinterpret_cast<const uint4*>(&lAB[4096 + q*256 + lane*4]);
        uint4 h01 = *reinterpret_cast<const uint4*>(&lH[wid][4*q]);
        uint4 h23 = *reinterpret_cast<const uint4*>(&lH[wid][4*q+2]);
        hf2 e0 = unpack2(bv.x), e1 = unpack2(bv.y);
        hf2 e2 = unpack2(bv.z), e3 = unpack2(bv.w);
        P0r = FDOT2(e0, unpack2(h01.x), P0r);
        P0i = FDOT2(e0, unpack2(h01.y), P0i);
        P0r = FDOT2(e1, unpack2(h01.z), P0r);
        P0i = FDOT2(e1, unpack2(h01.w), P0i);
        P0r = FDOT2(e2, unpack2(h23.x), P0r);
        P0i = FDOT2(e2, unpack2(h23.y), P0i);
        P0r = FDOT2(e3, unpack2(h23.z), P0r);
        P0i = FDOT2(e3, unpack2(h23.w), P0i);
    }
    #pragma unroll
    for (int q = 8; q < 16; ++q){
        uint4 bv  = *reinterpret_cast<const uint4*>(&lAB[4096 + q*256 + lane*4]);
        uint4 h01 = *reinterpret_cast<const uint4*>(&lH[wid][4*q]);
        uint4 h23 = *reinterpret_cast<const uint4*>(&lH[wid][4*q+2]);
        hf2 e0 = unpack2(bv.x), e1 = unpack2(bv.y);
        hf2 e2 = unpack2(bv.z), e3 = unpack2(bv.w);
        P1r = FDOT2(e0, unpack2(h01.x), P1r);
        P1i = FDOT2(e0, unpack2(h01.y), P1i);
        P1r = FDOT2(e1, unpack2(h01.z), P1r);
        P1i = FDOT2(e1, unpack2(h01.w), P1i);
        P1r = FDOT2(e2, unpack2(h23.x), P1r);
        P1i = FDOT2(e2, unpack2(h23.y), P1i);
        P1r = FDOT2(e3, unpack2(h23.z), P1r);
        P1i = FDOT2(e3, unpack2(h23.w), P1i);
    }
    float w0r = (v6.r0*P0r - v6.i0*P0i) + (v6.r1*P1r - v6.i1*P1i);
    float w0i = (v6.r0*P0i + v6.i0*P0r) + (v6.r1*P1i + v6.i1*P1r);
    float w1r = (v6.r1*P0r - v6.i1*P0i) + (v6.r0*P1r - v6.i0*P1i);
    float w1i = (v6.r1*P0i + v6.i1*P0r) + (v6.r0*P1i + v6.i0*P1r);

    // Row quadratics (lane = r) and col quadratics (lane = c)
    float a0 = u0r*u0r + u0i*u0i;
    float a1 = u1r*u1r + u1i*u1i;
    float zr = u0r*u1r + u0i*u1i;
    float zi = u0i*u1r - u0r*u1i;
    float b0 = w0r*w0r + w0i*w0i;
    float b1 = w1r*w1r + w1i*w1i;
    float yr = w0r*w1r + w0i*w1i;
    float yi = w0i*w1r - w0r*w1i;

    // Col plain sums (uniform) and row full-parity signed sums (uniformized)
    PLAIN6(b0, Pb0) PLAIN6(b1, Pb1) PLAIN6(yr, Pyr) PLAIN6(yi, Pyi)
    SBFLY(a0, Ta0) SBFLY(a1, Ta1) SBFLY(zr, Tzr) SBFLY(zi, Tzi)
    const float sgn = (__builtin_popcount((unsigned)lane) & 1) ? -1.f : 1.f;
    float SA0 = sgn*Ta0, SA1 = sgn*Ta1, SZr = sgn*Tzr, SZi = sgn*Tzi;

    // Per-lane bilinear combos, then one prefix-parity chain each
    float alpha = a0*Pb0 + a1*Pb1 + 2.f*(zr*Pyr - zi*Pyi);
    float beta  = SA0*b0 + SA1*b1 + 2.f*(SZr*yr - SZi*yi);
    CHAIN6(alpha, A_)
    CHAIN6(beta,  C_)

    if (lane == 0){
        float* o = out + (size_t)b * NQ;
        o[0]  = A_R0; o[1]  = A_R1; o[2]  = A_R2;
        o[3]  = A_R3; o[4]  = A_R4; o[5]  = A_R5;
        o[6]  = C_R0; o[7]  = C_R1; o[8]  = C_R2;
        o[9]  = C_R3; o[10] = C_R4; o[11] = C_R5;
    }
}

extern "C" void kernel_launch(void* const* d_in, const int* in_sizes, int n_in,
                              void* d_out, int out_size, void* d_ws, size_t ws_size,
                              hipStream_t stream){
    const float* x   = (const float*)d_in[0];
    const float* wts = (const float*)d_in[1];
    float* out = (float*)d_out;
    unsigned* AB = (unsigned*)d_ws;     // 32 KB f16 A/B matrices
    const int B = in_sizes[0] / NQ;

    build_AB<<<32, 256, 0, stream>>>(wts, AB);
    qsim<<<(B + 7) / 8, 512, 0, stream>>>(x, wts, AB, out, B);
}

// Round 10
// 25.075 us; speedup vs baseline: 38.8455x; 1.1143x over previous
//
#include <hip/hip_runtime.h>

#define NQ 12

typedef _Float16 hf2 __attribute__((ext_vector_type(2)));

#if defined(__has_builtin)
#if __has_builtin(__builtin_amdgcn_fdot2)
#define FDOT2(a,b,c) __builtin_amdgcn_fdot2((a),(b),(c),false)
#endif
#endif
#ifndef FDOT2
__device__ __forceinline__ float fdot2_sw(hf2 a, hf2 b, float c){
    return c + (float)a.x*(float)b.x + (float)a.y*(float)b.y;
}
#define FDOT2(a,b,c) fdot2_sw((a),(b),(c))
#endif

struct C2 { float r, i; };
__device__ __forceinline__ C2 cmul(C2 a, C2 b){ return C2{a.r*b.r - a.i*b.i, a.r*b.i + a.i*b.r}; }
__device__ __forceinline__ C2 cadd(C2 a, C2 b){ return C2{a.r + b.r, a.i + b.i}; }

struct V4 { float r0, i0, r1, i1; };

__device__ __forceinline__ unsigned pack2(float a, float b){
    union { hf2 h; unsigned u; } cv;
    cv.h.x = (_Float16)a; cv.h.y = (_Float16)b;
    return cv.u;
}
__device__ __forceinline__ hf2 unpack2(unsigned u){
    union { unsigned u; hf2 h; } cv; cv.u = u; return cv.h;
}
// broadcast lane L's packed value to all lanes (SGPR result feeds v_dot2 directly)
#define RL(v, L) ((unsigned)__builtin_amdgcn_readlane((int)(v), (L)))

// Fused per-wire unitary G = RZ(c)*RY(b)*RX(a) for weight-triple t -> 8 floats.
__device__ __forceinline__ void fused_gate(const float* __restrict__ wts, int t, float* o){
    float a = wts[3*t], bb = wts[3*t+1], c = wts[3*t+2];
    float sa, ca, sb, cb, sc, cc;
    sincosf(0.5f*a,  &sa, &ca);
    sincosf(0.5f*bb, &sb, &cb);
    sincosf(0.5f*c,  &sc, &cc);
    C2 rx00{ca,0.f}, rx01{0.f,-sa}, rx10{0.f,-sa}, rx11{ca,0.f};
    C2 ry00{cb,0.f}, ry01{-sb,0.f}, ry10{sb,0.f}, ry11{cb,0.f};
    C2 m00 = cadd(cmul(ry00,rx00), cmul(ry01,rx10));
    C2 m01 = cadd(cmul(ry00,rx01), cmul(ry01,rx11));
    C2 m10 = cadd(cmul(ry10,rx00), cmul(ry11,rx10));
    C2 m11 = cadd(cmul(ry10,rx01), cmul(ry11,rx11));
    C2 e0{cc,-sc}, e1{cc,sc};
    C2 g00 = cmul(e0,m00), g01 = cmul(e0,m01);
    C2 g10 = cmul(e1,m10), g11 = cmul(e1,m11);
    o[0]=g00.r; o[1]=g00.i; o[2]=g01.r; o[3]=g01.i;
    o[4]=g10.r; o[5]=g10.i; o[6]=g11.r; o[7]=g11.i;
}

// v_w = G0_w * [cos(x/2), sin(x/2)]^T ; g0 is GLOBAL with uniform address ->
// compiler emits scalar loads (SMEM pipe, off the DS critical path).
__device__ __forceinline__ V4 loadv(const float* __restrict__ g0, int w, float xw){
    float sx, cx;
    __sincosf(0.5f * xw, &sx, &cx);
    const float* g = g0 + w*8;
    V4 v;
    v.r0 = g[0]*cx + g[2]*sx;  v.i0 = g[1]*cx + g[3]*sx;
    v.r1 = g[4]*cx + g[6]*sx;  v.i1 = g[5]*cx + g[7]*sx;
    return v;
}

__device__ __forceinline__ void cmulsel(float& ar, float& ai, const V4& v, int bit){
    float br = bit ? v.r1 : v.r0;
    float bi = bit ? v.i1 : v.i0;
    float nr = ar*br - ai*bi, ni = ar*bi + ai*br;
    ar = nr; ai = ni;
}

// Build A = (x) G1_{0..5}, B = (x) G1_{6..11} (64x64, f16 complex), with
// 4-COLUMN-GROUP layout: entry (row, col) at
//   part*4096 + (col>>2)*256 + row*4 + (col&3)
// so a lane's 4 consecutive columns for its row are one 16-byte read.
// Block 0 additionally exports layer-0 gates (t=0..11, 96 floats) to g0out.
__global__ void build_AB(const float* __restrict__ wts, unsigned* __restrict__ AB,
                         float* __restrict__ g0out){
    __shared__ float sG[192];
    const int tid = threadIdx.x;
    if (tid < 24) fused_gate(wts, tid, sG + tid*8);
    __syncthreads();
    if (blockIdx.x == 0 && tid < 96) g0out[tid] = sG[tid];
    const int idx  = blockIdx.x * 256 + tid;    // 0..8191
    const int part = idx >> 12;                 // 0 = A (gates 12..17), 1 = B
    const int e    = idx & 4095;
    const int row  = e & 63;
    const int col  = e >> 6;
    const float* gb = sG + (part ? 18*8 : 12*8);
    float cr = 1.f, ci = 0.f;
    #pragma unroll
    for (int w = 0; w < 6; ++w){
        int rb = (row >> (5-w)) & 1;
        int cb = (col >> (5-w)) & 1;
        const float* g = gb + w*8 + (rb*2+cb)*2;
        float ar = g[0], ai = g[1];
        float nr = cr*ar - ci*ai, ni = cr*ai + ci*ar;
        cr = nr; ci = ni;
    }
    AB[part*4096 + (col>>2)*256 + row*4 + (col&3)] = pack2(cr, ci);
}

// CHAIN6: prefix-parity signed reductions, P##R_w = sum_r (-1)^{parity(r>>(5-w))} v[r],
// valid at lane 0.
#define CHAIN6(v, P) \
    float P##d1 = (v) - __shfl_xor((v),32); \
    float P##d2 = P##d1 - __shfl_xor(P##d1,16); \
    float P##d3 = P##d2 - __shfl_xor(P##d2,8); \
    float P##d4 = P##d3 - __shfl_xor(P##d3,4); \
    float P##d5 = P##d4 - __shfl_xor(P##d4,2); \
    float P##R5 = P##d5 - __shfl_xor(P##d5,1); \
    float P##R0 = P##d1; P##R0 += __shfl_xor(P##R0,16); P##R0 += __shfl_xor(P##R0,8); \
        P##R0 += __shfl_xor(P##R0,4); P##R0 += __shfl_xor(P##R0,2); P##R0 += __shfl_xor(P##R0,1); \
    float P##R1 = P##d2; P##R1 += __shfl_xor(P##R1,8); P##R1 += __shfl_xor(P##R1,4); \
        P##R1 += __shfl_xor(P##R1,2); P##R1 += __shfl_xor(P##R1,1); \
    float P##R2 = P##d3; P##R2 += __shfl_xor(P##R2,4); P##R2 += __shfl_xor(P##R2,2); P##R2 += __shfl_xor(P##R2,1); \
    float P##R3 = P##d4; P##R3 += __shfl_xor(P##R3,2); P##R3 += __shfl_xor(P##R3,1); \
    float P##R4 = P##d5; P##R4 += __shfl_xor(P##R4,1);

// PLAIN6: full sum, uniform across lanes.
#define PLAIN6(v, name) \
    float name = (v); name += __shfl_xor(name,32); name += __shfl_xor(name,16); \
    name += __shfl_xor(name,8); name += __shfl_xor(name,4); name += __shfl_xor(name,2); name += __shfl_xor(name,1);

// SBFLY: signed all-reduce butterfly; lane l ends with
// (-1)^{popcount(l)} * sum_r (-1)^{popcount(r)} v_r  (multiply by sgn to uniformize).
#define SBFLY(v, name) \
    float name = (v) - __shfl_xor((v),32); \
    name = name - __shfl_xor(name,16); \
    name = name - __shfl_xor(name,8); \
    name = name - __shfl_xor(name,4); \
    name = name - __shfl_xor(name,2); \
    name = name - __shfl_xor(name,1);

// Rank-2 evaluation (one wave = one batch element):
// S[j][l] = H2[j]*LP_{j&1}[l]; layer-1 = A (x) B, so
// D = u0 (x) w0 + u1 (x) w1, u_p = A*(H2 masked to j&1==p), w_p from the
// wire-6 split of B*base. 12 outputs = separable prefix-parity reductions:
//   o[w]   = CHAIN6(alpha).Rw,  alpha_r = a0*Pb0 + a1*Pb1 + 2(zr*Pyr - zi*Pyi)
//   o[6+m] = CHAIN6(beta).Rm,   beta_c  = SA0*b0 + SA1*b1 + 2(SZr*yr - SZi*yi)
// H2/base live in per-lane registers; column broadcast via v_readlane -> SGPR
// feeding v_dot2_f32_f16 (no LDS on the broadcast path).
__global__ __launch_bounds__(512)
void qsim(const float* __restrict__ x, const float* __restrict__ g0,
          const unsigned* __restrict__ AB, float* __restrict__ out, int B){
    __shared__ __align__(16) unsigned lAB[8192];   // 32 KB A,B f16 pairs

    const int tid = threadIdx.x;
    {   // stage A,B (L2-resident after first blocks)
        const uint4* src = reinterpret_cast<const uint4*>(AB);
        uint4* dst = reinterpret_cast<uint4*>(lAB);
        #pragma unroll
        for (int k = 0; k < 4; ++k) dst[tid + k*512] = src[tid + k*512];
    }
    __syncthreads();

    const int lane = tid & 63;
    const int wid  = tid >> 6;
    const int b    = blockIdx.x * 8 + wid;
    if (b >= B) return;

    // x for this element: 3 x float4 (48 B, 16-aligned)
    const float4* xv = reinterpret_cast<const float4*>(x + (size_t)b * NQ);
    float4 xa = xv[0], xb = xv[1], xc = xv[2];

    V4 v0  = loadv(g0, 0,  xa.x);
    V4 v1  = loadv(g0, 1,  xa.y);
    V4 v2  = loadv(g0, 2,  xa.z);
    V4 v3  = loadv(g0, 3,  xa.w);
    V4 v4  = loadv(g0, 4,  xb.x);
    V4 v5  = loadv(g0, 5,  xb.y);
    V4 v6  = loadv(g0, 6,  xb.z);
    V4 v7  = loadv(g0, 7,  xb.w);
    V4 v8  = loadv(g0, 8,  xc.x);
    V4 v9  = loadv(g0, 9,  xc.y);
    V4 v10 = loadv(g0, 10, xc.z);
    V4 v11 = loadv(g0, 11, xc.w);

    // H2[j], j = lane: gray product over wires 0..5 (wire0 <-> bit5) -> packed regs
    unsigned hx, hy;
    {
        const int g0b = (lane>>5)&1;
        const int g1b = ((lane>>4)^(lane>>5))&1;
        const int g2b = ((lane>>3)^(lane>>4))&1;
        const int g3b = ((lane>>2)^(lane>>3))&1;
        const int g4b = ((lane>>1)^(lane>>2))&1;
        const int g5b = ( lane    ^(lane>>1))&1;
        float hr_ = g0b ? v0.r1 : v0.r0;
        float hi_ = g0b ? v0.i1 : v0.i0;
        cmulsel(hr_, hi_, v1, g1b);
        cmulsel(hr_, hi_, v2, g2b);
        cmulsel(hr_, hi_, v3, g3b);
        cmulsel(hr_, hi_, v4, g4b);
        cmulsel(hr_, hi_, v5, g5b);
        hx = pack2(hr_, -hi_);
        hy = pack2(hi_, hr_);
    }
    // base over wires 7..11 -> packed regs
    unsigned bx, by;
    {
        const int b1 = ((lane>>4)^(lane>>5))&1;   // wire 7
        const int b2 = ((lane>>3)^(lane>>4))&1;   // wire 8
        const int b3 = ((lane>>2)^(lane>>3))&1;   // wire 9
        const int b4 = ((lane>>1)^(lane>>2))&1;   // wire 10
        const int b5 = ( lane    ^(lane>>1))&1;   // wire 11
        float br_ = b1 ? v7.r1 : v7.r0;
        float bi_ = b1 ? v7.i1 : v7.i0;
        cmulsel(br_, bi_, v8,  b2);
        cmulsel(br_, bi_, v9,  b3);
        cmulsel(br_, bi_, v10, b4);
        cmulsel(br_, bi_, v11, b5);
        bx = pack2(br_, -bi_);
        by = pack2(bi_, br_);
    }

    // u_p[r] = sum_{j: j&1==p} A[r][j]*H2[j]; per 4 cols: 1 b128 row read +
    // 8 readlane broadcasts + 8 fdot2.
    float u0r=0.f,u0i=0.f,u1r=0.f,u1i=0.f;
    #pragma unroll
    for (int q = 0; q < 16; ++q){
        uint4 av = *reinterpret_cast<const uint4*>(&lAB[q*256 + lane*4]);
        u0r = FDOT2(unpack2(av.x), unpack2(RL(hx, 4*q+0)), u0r);
        u0i = FDOT2(unpack2(av.x), unpack2(RL(hy, 4*q+0)), u0i);
        u1r = FDOT2(unpack2(av.y), unpack2(RL(hx, 4*q+1)), u1r);
        u1i = FDOT2(unpack2(av.y), unpack2(RL(hy, 4*q+1)), u1i);
        u0r = FDOT2(unpack2(av.z), unpack2(RL(hx, 4*q+2)), u0r);
        u0i = FDOT2(unpack2(av.z), unpack2(RL(hy, 4*q+2)), u0i);
        u1r = FDOT2(unpack2(av.w), unpack2(RL(hx, 4*q+3)), u1r);
        u1i = FDOT2(unpack2(av.w), unpack2(RL(hy, 4*q+3)), u1i);
    }

    // P_h[c] = sum_{l: bit5(l)==h} B[c][l]*base[l]
    float P0r=0.f,P0i=0.f,P1r=0.f,P1i=0.f;
    #pragma unroll
    for (int q = 0; q < 8; ++q){
        uint4 bv = *reinterpret_cast<const uint4*>(&lAB[4096 + q*256 + lane*4]);
        P0r = FDOT2(unpack2(bv.x), unpack2(RL(bx, 4*q+0)), P0r);
        P0i = FDOT2(unpack2(bv.x), unpack2(RL(by, 4*q+0)), P0i);
        P0r = FDOT2(unpack2(bv.y), unpack2(RL(bx, 4*q+1)), P0r);
        P0i = FDOT2(unpack2(bv.y), unpack2(RL(by, 4*q+1)), P0i);
        P0r = FDOT2(unpack2(bv.z), unpack2(RL(bx, 4*q+2)), P0r);
        P0i = FDOT2(unpack2(bv.z), unpack2(RL(by, 4*q+2)), P0i);
        P0r = FDOT2(unpack2(bv.w), unpack2(RL(bx, 4*q+3)), P0r);
        P0i = FDOT2(unpack2(bv.w), unpack2(RL(by, 4*q+3)), P0i);
    }
    #pragma unroll
    for (int q = 8; q < 16; ++q){
        uint4 bv = *reinterpret_cast<const uint4*>(&lAB[4096 + q*256 + lane*4]);
        P1r = FDOT2(unpack2(bv.x), unpack2(RL(bx, 4*q+0)), P1r);
        P1i = FDOT2(unpack2(bv.x), unpack2(RL(by, 4*q+0)), P1i);
        P1r = FDOT2(unpack2(bv.y), unpack2(RL(bx, 4*q+1)), P1r);
        P1i = FDOT2(unpack2(bv.y), unpack2(RL(by, 4*q+1)), P1i);
        P1r = FDOT2(unpack2(bv.z), unpack2(RL(bx, 4*q+2)), P1r);
        P1i = FDOT2(unpack2(bv.z), unpack2(RL(by, 4*q+2)), P1i);
        P1r = FDOT2(unpack2(bv.w), unpack2(RL(bx, 4*q+3)), P1r);
        P1i = FDOT2(unpack2(bv.w), unpack2(RL(by, 4*q+3)), P1i);
    }
    float w0r = (v6.r0*P0r - v6.i0*P0i) + (v6.r1*P1r - v6.i1*P1i);
    float w0i = (v6.r0*P0i + v6.i0*P0r) + (v6.r1*P1i + v6.i1*P1r);
    float w1r = (v6.r1*P0r - v6.i1*P0i) + (v6.r0*P1r - v6.i0*P1i);
    float w1i = (v6.r1*P0i + v6.i1*P0r) + (v6.r0*P1i + v6.i0*P1r);

    // Row quadratics (lane = r) and col quadratics (lane = c)
    float a0 = u0r*u0r + u0i*u0i;
    float a1 = u1r*u1r + u1i*u1i;
    float zr = u0r*u1r + u0i*u1i;
    float zi = u0i*u1r - u0r*u1i;
    float b0 = w0r*w0r + w0i*w0i;
    float b1 = w1r*w1r + w1i*w1i;
    float yr = w0r*w1r + w0i*w1i;
    float yi = w0i*w1r - w0r*w1i;

    // Col plain sums (uniform) and row full-parity signed sums (uniformized)
    PLAIN6(b0, Pb0) PLAIN6(b1, Pb1) PLAIN6(yr, Pyr) PLAIN6(yi, Pyi)
    SBFLY(a0, Ta0) SBFLY(a1, Ta1) SBFLY(zr, Tzr) SBFLY(zi, Tzi)
    const float sgn = (__builtin_popcount((unsigned)lane) & 1) ? -1.f : 1.f;
    float SA0 = sgn*Ta0, SA1 = sgn*Ta1, SZr = sgn*Tzr, SZi = sgn*Tzi;

    // Per-lane bilinear combos, then one prefix-parity chain each
    float alpha = a0*Pb0 + a1*Pb1 + 2.f*(zr*Pyr - zi*Pyi);
    float beta  = SA0*b0 + SA1*b1 + 2.f*(SZr*yr - SZi*yi);
    CHAIN6(alpha, A_)
    CHAIN6(beta,  C_)

    if (lane == 0){
        float* o = out + (size_t)b * NQ;
        o[0]  = A_R0; o[1]  = A_R1; o[2]  = A_R2;
        o[3]  = A_R3; o[4]  = A_R4; o[5]  = A_R5;
        o[6]  = C_R0; o[7]  = C_R1; o[8]  = C_R2;
        o[9]  = C_R3; o[10] = C_R4; o[11] = C_R5;
    }
}

extern "C" void kernel_launch(void* const* d_in, const int* in_sizes, int n_in,
                              void* d_out, int out_size, void* d_ws, size_t ws_size,
                              hipStream_t stream){
    const float* x   = (const float*)d_in[0];
    const float* wts = (const float*)d_in[1];
    float* out = (float*)d_out;
    unsigned* AB = (unsigned*)d_ws;                       // 32 KB f16 A/B
    float* g0buf = (float*)((char*)d_ws + 32768);         // 96 floats, layer-0 gates
    const int B = in_sizes[0] / NQ;

    build_AB<<<32, 256, 0, stream>>>(wts, AB, g0buf);
    qsim<<<(B + 7) / 8, 512, 0, stream>>>(x, g0buf, AB, out, B);
}